// Round 1
// baseline (2894.881 us; speedup 1.0000x reference)
//
#include <hip/hip_runtime.h>

#define NN   50000      // nodes
#define NF   64         // input features
#define NDIM 128        // hidden / output dim (2F == D == 128)
#define NE   600000     // edges
#define NM   3          // graphs
#define NTOT (NN * NDIM)

// ---------------------------------------------------------------- utilities
__global__ void k_fill(float* __restrict__ p, float v, int n) {
    int i = blockIdx.x * blockDim.x + threadIdx.x;
    if (i < n) p[i] = v;
}

__global__ void k_deg_scatter(const int* __restrict__ col, const float* __restrict__ ew,
                              float* __restrict__ deg) {
    int e = blockIdx.x * blockDim.x + threadIdx.x;
    if (e < NE) atomicAdd(&deg[col[e]], ew[e]);
}

__global__ void k_rsqrt(float* __restrict__ p, int n) {
    int i = blockIdx.x * blockDim.x + threadIdx.x;
    if (i < n) p[i] = rsqrtf(p[i]);   // deg >= 1 always (self-loop)
}

// ---------------------------------------------------------------- GEMM: out[n,o] = sum_k A[n,k] * W[k,o]
// block = 256 threads = 2 rows x 128 cols
template<int K>
__global__ void k_rowgemm(const float* __restrict__ A, const float* __restrict__ W,
                          float* __restrict__ out) {
    __shared__ float arow[2][K];
    int row0 = blockIdx.x * 2;
    for (int i = threadIdx.x; i < 2 * K; i += 256) {
        int rr = i / K, kk = i - rr * K;
        int g = row0 + rr;
        arow[rr][kk] = (g < NN) ? A[(size_t)g * K + kk] : 0.f;
    }
    __syncthreads();
    int r = threadIdx.x >> 7;
    int o = threadIdx.x & 127;
    int row = row0 + r;
    if (row >= NN) return;
    float acc = 0.f;
#pragma unroll 8
    for (int k = 0; k < K; ++k) acc = fmaf(arow[r][k], W[k * NDIM + o], acc);
    out[(size_t)row * NDIM + o] = acc;
}

// ---------------------------------------------------------------- aggregation
// self-loop term: out[n,:] = XW[n,:] * dis[n]^2
__global__ void k_selfinit(const float* __restrict__ xw, const float* __restrict__ dis,
                           float* __restrict__ out) {
    int i = blockIdx.x * blockDim.x + threadIdx.x;
    if (i < NTOT) {
        float d = dis[i >> 7];
        out[i] = xw[i] * d * d;
    }
}

// edges: out[col,:] += XW[row,:] * dis[row]*ew*dis[col]; 2 edges per 256-thread block
__global__ void k_edge_scatter(const int* __restrict__ row, const int* __restrict__ col,
                               const float* __restrict__ ew, const float* __restrict__ dis,
                               const float* __restrict__ xw, float* __restrict__ out) {
    int e = blockIdx.x * 2 + (threadIdx.x >> 7);
    if (e >= NE) return;
    int d = threadIdx.x & 127;
    int r = row[e], c = col[e];
    float nrm = dis[r] * ew[e] * dis[c];
    atomicAdd(&out[(size_t)c * NDIM + d], xw[(size_t)r * NDIM + d] * nrm);
}

// ---------------------------------------------------------------- BatchNorm (training stats) + ReLU
// stat[0..127] = column sums, stat[128..255] = column sum-of-squares
__global__ void k_bnstats(const float* __restrict__ x, float* __restrict__ stat) {
    int d = threadIdx.x;   // 128 threads
    float s = 0.f, s2 = 0.f;
    for (int n = blockIdx.x; n < NN; n += gridDim.x) {
        float v = x[(size_t)n * NDIM + d];
        s += v;
        s2 = fmaf(v, v, s2);
    }
    atomicAdd(&stat[d], s);
    atomicAdd(&stat[128 + d], s2);
}

__global__ void k_bnfinal(const float* __restrict__ stat, float* __restrict__ mi) {
    int d = threadIdx.x;   // 128 threads
    float m = stat[d] * (1.f / (float)NN);
    float v = stat[128 + d] * (1.f / (float)NN) - m * m;  // biased var (torch BN)
    mi[d] = m;
    mi[128 + d] = rsqrtf(v + 1e-5f);
}

// x = relu((x - mean) * invstd), optionally accumulating sum(x) for the SE pool
template<bool ACC>
__global__ void k_bnapply(float* __restrict__ x, const float* __restrict__ mi,
                          float* __restrict__ ssum) {
    __shared__ float red[256];
    float local = 0.f;
    for (int i = blockIdx.x * blockDim.x + threadIdx.x; i < NTOT;
         i += gridDim.x * blockDim.x) {
        int d = i & 127;
        float v = (x[i] - mi[d]) * mi[128 + d];
        v = fmaxf(v, 0.f);
        x[i] = v;
        if (ACC) local += v;
    }
    if (ACC) {
        red[threadIdx.x] = local;
        __syncthreads();
        for (int s = 128; s > 0; s >>= 1) {
            if (threadIdx.x < s) red[threadIdx.x] += red[threadIdx.x + s];
            __syncthreads();
        }
        if (threadIdx.x == 0) atomicAdd(ssum, red[0]);
    }
}

// ---------------------------------------------------------------- SE attention -> folded conv weight
// Wc[(m*128+d)*128 + o] = y[m] * cnn_w[o, m, d]
__global__ void k_attn_wc(const float* __restrict__ ssum, const float* __restrict__ fc1w,
                          const float* __restrict__ fc1b, const float* __restrict__ fc2w,
                          const float* __restrict__ fc2b, const float* __restrict__ cnnw,
                          float* __restrict__ Wc) {
    __shared__ float ysh[NM];
    if (threadIdx.x == 0) {
        float s[NM], h[6 * NM];
        for (int m = 0; m < NM; ++m) s[m] = ssum[m] * (1.f / (float)NTOT);
        for (int j = 0; j < 6 * NM; ++j) {
            float a = fc1b[j];
            for (int m = 0; m < NM; ++m) a = fmaf(s[m], fc1w[j * NM + m], a);
            h[j] = fmaxf(a, 0.f);
        }
        for (int m = 0; m < NM; ++m) {
            float a = fc2b[m];
            for (int j = 0; j < 6 * NM; ++j) a = fmaf(h[j], fc2w[m * 6 * NM + j], a);
            ysh[m] = 1.f / (1.f + expf(-a));
        }
    }
    __syncthreads();
    for (int idx = threadIdx.x; idx < NM * NDIM * NDIM; idx += blockDim.x) {
        int o = idx & 127;
        int k = idx >> 7;      // m*128 + d
        int m = k >> 7;
        Wc[idx] = ysh[m] * cnnw[o * (NM * NDIM) + k];
    }
}

// ---------------------------------------------------------------- final GEMM: out[n,o] = cnnb[o] + sum_k arow[k]*Wc[k,o]
// A-row is concat(x2_0[n], x2_1[n], x2_2[n]); x2_2 may alias `out` (each block
// reads only the rows it later writes; __syncthreads separates the phases).
__global__ void k_final(const float* __restrict__ x0, const float* __restrict__ x1,
                        const float* __restrict__ x2, const float* __restrict__ Wc,
                        const float* __restrict__ cnnb, float* __restrict__ out) {
    __shared__ float arow[2][NM * NDIM];
    int row0 = blockIdx.x * 2;
    for (int i = threadIdx.x; i < 2 * NM * NDIM; i += 256) {
        int rr = (i >= NM * NDIM) ? 1 : 0;
        int kk = i - rr * NM * NDIM;
        int g = row0 + rr;
        if (g < NN) {
            const float* src = (kk < NDIM) ? x0 : (kk < 2 * NDIM ? x1 : x2);
            arow[rr][kk] = src[(size_t)g * NDIM + (kk & 127)];
        } else {
            arow[rr][kk] = 0.f;
        }
    }
    __syncthreads();
    int r = threadIdx.x >> 7;
    int o = threadIdx.x & 127;
    int row = row0 + r;
    if (row >= NN) return;
    float acc = cnnb[o];
#pragma unroll 8
    for (int k = 0; k < NM * NDIM; ++k) acc = fmaf(arow[r][k], Wc[k * NDIM + o], acc);
    out[(size_t)row * NDIM + o] = acc;
}

// ================================================================ launch
extern "C" void kernel_launch(void* const* d_in, const int* in_sizes, int n_in,
                              void* d_out, int out_size, void* d_ws, size_t ws_size,
                              hipStream_t stream) {
    const float* feat = (const float*)d_in[0];   // [3,50000,64]
    const int*   adj  = (const int*)d_in[1];     // [3,2,600000]
    const float* ew   = (const float*)d_in[2];   // [3,600000]
    const float* w1   = (const float*)d_in[3];   // [64,128]
    const float* w2   = (const float*)d_in[5];   // [128,128]
    const float* fc1w = (const float*)d_in[7];   // [18,3]
    const float* fc1b = (const float*)d_in[8];   // [18]
    const float* fc2w = (const float*)d_in[9];   // [3,18]
    const float* fc2b = (const float*)d_in[10];  // [3]
    const float* cnnw = (const float*)d_in[11];  // [128,3,128,1]
    const float* cnnb = (const float*)d_in[12];  // [128]
    float* out = (float*)d_out;

    float* ws = (float*)d_ws;
    size_t off = 0;
    float* bufA = ws + off; off += NTOT;   // GEMM output
    float* bufB = ws + off; off += NTOT;   // layer-1 aggregate / x1
    float* x2b[NM];
    x2b[0] = ws + off; off += NTOT;
    x2b[1] = ws + off; off += NTOT;
    x2b[2] = out;                          // d_out doubles as branch-2 scratch
    float* dis  = ws + off; off += NN;
    float* stat = ws + off; off += 256;
    float* mi   = ws + off; off += 256;
    float* ssum = ws + off; off += 4;
    float* Wc   = ws + off; off += NM * NDIM * NDIM;

    k_fill<<<1, 64, 0, stream>>>(ssum, 0.f, 4);

    for (int m = 0; m < NM; ++m) {
        const float* fm   = feat + (size_t)m * NN * NF;
        const int*   rowp = adj + (size_t)m * 2 * NE;
        const int*   colp = rowp + NE;
        const float* ewm  = ew + (size_t)m * NE;
        float* x2 = x2b[m];

        // degrees -> dis = rsqrt(1 + sum_in(ew))
        k_fill<<<(NN + 255) / 256, 256, 0, stream>>>(dis, 1.0f, NN);
        k_deg_scatter<<<(NE + 255) / 256, 256, 0, stream>>>(colp, ewm, dis);
        k_rsqrt<<<(NN + 255) / 256, 256, 0, stream>>>(dis, NN);

        // ---- layer 1: X@W1 -> aggregate -> BN+ReLU (bias cancels in BN)
        k_rowgemm<NF><<<NN / 2, 256, 0, stream>>>(fm, w1, bufA);
        k_selfinit<<<(NTOT + 255) / 256, 256, 0, stream>>>(bufA, dis, bufB);
        k_edge_scatter<<<NE / 2, 256, 0, stream>>>(rowp, colp, ewm, dis, bufA, bufB);
        k_fill<<<1, 256, 0, stream>>>(stat, 0.f, 256);
        k_bnstats<<<512, 128, 0, stream>>>(bufB, stat);
        k_bnfinal<<<1, 128, 0, stream>>>(stat, mi);
        k_bnapply<false><<<1024, 256, 0, stream>>>(bufB, mi, nullptr);

        // ---- layer 2: X1@W2 -> aggregate -> BN+ReLU (+ SE mean accumulation)
        k_rowgemm<NDIM><<<NN / 2, 256, 0, stream>>>(bufB, w2, bufA);
        k_selfinit<<<(NTOT + 255) / 256, 256, 0, stream>>>(bufA, dis, x2);
        k_edge_scatter<<<NE / 2, 256, 0, stream>>>(rowp, colp, ewm, dis, bufA, x2);
        k_fill<<<1, 256, 0, stream>>>(stat, 0.f, 256);
        k_bnstats<<<512, 128, 0, stream>>>(x2, stat);
        k_bnfinal<<<1, 128, 0, stream>>>(stat, mi);
        k_bnapply<true><<<1024, 256, 0, stream>>>(x2, mi, ssum + m);
    }

    // SE attention -> folded weight, then final [N,384]@[384,128] GEMM
    k_attn_wc<<<1, 256, 0, stream>>>(ssum, fc1w, fc1b, fc2w, fc2b, cnnw, Wc);
    k_final<<<NN / 2, 256, 0, stream>>>(x2b[0], x2b[1], x2b[2], Wc, cnnb, out);
}

// Round 2
// 2083.660 us; speedup vs baseline: 1.3893x; 1.3893x over previous
//
#include <hip/hip_runtime.h>

#define NN   50000      // nodes
#define NF   64         // input features
#define NDIM 128        // hidden / output dim
#define NE   600000     // edges
#define NM   3          // graphs
#define NTOT (NN * NDIM)
#define NB_SCAN 196     // ceil(NN/256)

// ---------------------------------------------------------------- utilities
__global__ void k_fill(float* __restrict__ p, float v, int n) {
    int i = blockIdx.x * blockDim.x + threadIdx.x;
    if (i < n) p[i] = v;
}

// deg (float, pre-filled 1.0 for self loop) and cnt (int, zeroed) in one pass
__global__ void k_deg_count(const int* __restrict__ col, const float* __restrict__ ew,
                            float* __restrict__ deg, int* __restrict__ cnt) {
    int e = blockIdx.x * blockDim.x + threadIdx.x;
    if (e < NE) {
        int c = col[e];
        atomicAdd(&deg[c], ew[e]);
        atomicAdd(&cnt[c], 1);
    }
}

__global__ void k_rsqrt(float* __restrict__ p, int n) {
    int i = blockIdx.x * blockDim.x + threadIdx.x;
    if (i < n) p[i] = rsqrtf(p[i]);   // deg >= 1 always (self-loop)
}

// ---------------------------------------------------------------- CSR build (3-kernel scan + ticket fill)
__global__ void k_scan1(const int* __restrict__ cnt, int* __restrict__ ptr,
                        int* __restrict__ bsum) {
    __shared__ int s[256];
    int i = blockIdx.x * 256 + threadIdx.x;
    int v = (i < NN) ? cnt[i] : 0;
    s[threadIdx.x] = v;
    __syncthreads();
    for (int off = 1; off < 256; off <<= 1) {
        int x = (threadIdx.x >= off) ? s[threadIdx.x - off] : 0;
        __syncthreads();
        s[threadIdx.x] += x;
        __syncthreads();
    }
    if (i < NN) ptr[i] = s[threadIdx.x] - v;          // chunk-local exclusive
    if (threadIdx.x == 255) bsum[blockIdx.x] = s[255]; // chunk total
}

__global__ void k_scan2(int* __restrict__ bsum) {       // exclusive scan of chunk totals
    __shared__ int s[256];
    int t = threadIdx.x;
    int v = (t < NB_SCAN) ? bsum[t] : 0;
    s[t] = v;
    __syncthreads();
    for (int off = 1; off < 256; off <<= 1) {
        int x = (t >= off) ? s[t - off] : 0;
        __syncthreads();
        s[t] += x;
        __syncthreads();
    }
    bsum[t] = s[t] - v;
}

__global__ void k_scan3(int* __restrict__ ptr, const int* __restrict__ bsum,
                        int* __restrict__ cnt) {
    int i = blockIdx.x * 256 + threadIdx.x;
    if (i < NN) {
        ptr[i] += bsum[i >> 8];
        cnt[i] = 0;                                    // becomes the ticket counter
    }
    if (i == 0) ptr[NN] = NE;
}

// epack[j] = (src_row, bitcast(norm)) in CSR-by-col order
__global__ void k_fill_csr(const int* __restrict__ row, const int* __restrict__ col,
                           const float* __restrict__ ew, const float* __restrict__ dis,
                           const int* __restrict__ ptr, int* __restrict__ fill,
                           int2* __restrict__ epack) {
    int e = blockIdx.x * blockDim.x + threadIdx.x;
    if (e >= NE) return;
    int r = row[e], c = col[e];
    int slot = atomicAdd(&fill[c], 1);
    float nrm = dis[r] * ew[e] * dis[c];
    epack[ptr[c] + slot] = make_int2(r, __float_as_int(nrm));
}

// ---------------------------------------------------------------- GEMM: out[n,o] = sum_k A[n,k]*W[k,o]
// 16 rows/block, 256 thr = 16 rows x 16 colgroups, 8 cols (=8 indep acc) per thread.
// BN: apply relu((a-mu)*inv) to A elements on LDS load (K must be 128 then).
template<int K, bool BN>
__global__ void k_gemm(const float* __restrict__ A, const float* __restrict__ W,
                       const float* __restrict__ mi, float* __restrict__ out) {
    __shared__ float arow[16][K + 1];
    int row0 = blockIdx.x * 16;
    for (int i = threadIdx.x; i < 16 * K; i += 256) {
        int rr = i / K, kk = i - rr * K;
        int g = row0 + rr;
        float v = (g < NN) ? A[(size_t)g * K + kk] : 0.f;
        if (BN) v = fmaxf((v - mi[kk]) * mi[128 + kk], 0.f);
        arow[rr][kk] = v;
    }
    __syncthreads();
    int rrow = threadIdx.x >> 4;
    int o0 = (threadIdx.x & 15) * 8;
    float acc[8] = {0.f, 0.f, 0.f, 0.f, 0.f, 0.f, 0.f, 0.f};
#pragma unroll 4
    for (int k = 0; k < K; ++k) {
        float a = arow[rrow][k];
        const float4* wq = reinterpret_cast<const float4*>(W + k * NDIM + o0);
        float4 w0 = wq[0], w1 = wq[1];
        acc[0] = fmaf(a, w0.x, acc[0]); acc[1] = fmaf(a, w0.y, acc[1]);
        acc[2] = fmaf(a, w0.z, acc[2]); acc[3] = fmaf(a, w0.w, acc[3]);
        acc[4] = fmaf(a, w1.x, acc[4]); acc[5] = fmaf(a, w1.y, acc[5]);
        acc[6] = fmaf(a, w1.z, acc[6]); acc[7] = fmaf(a, w1.w, acc[7]);
    }
    int grow = row0 + rrow;
    if (grow < NN) {
        float4 r0 = {acc[0], acc[1], acc[2], acc[3]};
        float4 r1 = {acc[4], acc[5], acc[6], acc[7]};
        float4* op = reinterpret_cast<float4*>(out + (size_t)grow * NDIM + o0);
        op[0] = r0; op[1] = r1;
    }
}

// ---------------------------------------------------------------- CSR gather aggregation
// out[c,:] = xw[c,:]*dis[c]^2 + sum_{j in csr(c)} xw[src_j,:]*nrm_j
// 2 nodes/block (2 waves each), d = tid&127, register accumulation, no atomics.
__global__ void k_gather(const float* __restrict__ xw, const float* __restrict__ dis,
                         const int* __restrict__ ptr, const int2* __restrict__ epack,
                         float* __restrict__ out) {
    int c = blockIdx.x * 2 + (threadIdx.x >> 7);
    int d = threadIdx.x & 127;
    if (c >= NN) return;
    float ds = dis[c];
    float acc = xw[(size_t)c * NDIM + d] * ds * ds;
    int j1 = ptr[c + 1];
    for (int j = ptr[c]; j < j1; ++j) {
        int2 ep = epack[j];
        acc = fmaf(xw[(size_t)ep.x * NDIM + d], __int_as_float(ep.y), acc);
    }
    out[(size_t)c * NDIM + d] = acc;
}

// ---------------------------------------------------------------- BatchNorm stats
__global__ void k_bnstats(const float* __restrict__ x, float* __restrict__ stat) {
    int d = threadIdx.x & 127;
    int sub = threadIdx.x >> 7;
    float s = 0.f, s2 = 0.f;
    for (int n = blockIdx.x * 2 + sub; n < NN; n += gridDim.x * 2) {
        float v = x[(size_t)n * NDIM + d];
        s += v;
        s2 = fmaf(v, v, s2);
    }
    __shared__ float red[256];
    red[threadIdx.x] = s;
    __syncthreads();
    if (threadIdx.x < 128) atomicAdd(&stat[threadIdx.x], red[threadIdx.x] + red[threadIdx.x + 128]);
    __syncthreads();
    red[threadIdx.x] = s2;
    __syncthreads();
    if (threadIdx.x < 128) atomicAdd(&stat[128 + threadIdx.x], red[threadIdx.x] + red[threadIdx.x + 128]);
}

__global__ void k_bnfinal(const float* __restrict__ stat, float* __restrict__ mi) {
    int d = threadIdx.x;   // 128 threads
    float m = stat[d] * (1.f / (float)NN);
    float v = stat[128 + d] * (1.f / (float)NN) - m * m;  // biased var (torch BN)
    mi[d] = m;
    mi[128 + d] = rsqrtf(v + 1e-5f);
}

// sum of relu((x-mu)*inv) over everything, WITHOUT writing x (x stays raw)
__global__ void k_bnsum(const float* __restrict__ x, const float* __restrict__ mi,
                        float* __restrict__ ssum) {
    __shared__ float red[256];
    float local = 0.f;
    for (int i = blockIdx.x * blockDim.x + threadIdx.x; i < NTOT;
         i += gridDim.x * blockDim.x) {
        int d = i & 127;
        local += fmaxf((x[i] - mi[d]) * mi[128 + d], 0.f);
    }
    red[threadIdx.x] = local;
    __syncthreads();
    for (int s = 128; s > 0; s >>= 1) {
        if (threadIdx.x < s) red[threadIdx.x] += red[threadIdx.x + s];
        __syncthreads();
    }
    if (threadIdx.x == 0) atomicAdd(ssum, red[0]);
}

// ---------------------------------------------------------------- SE attention -> folded conv weight
__global__ void k_attn_wc(const float* __restrict__ ssum, const float* __restrict__ fc1w,
                          const float* __restrict__ fc1b, const float* __restrict__ fc2w,
                          const float* __restrict__ fc2b, const float* __restrict__ cnnw,
                          float* __restrict__ Wc) {
    __shared__ float ysh[NM];
    if (threadIdx.x == 0) {
        float s[NM], h[6 * NM];
        for (int m = 0; m < NM; ++m) s[m] = ssum[m] * (1.f / (float)NTOT);
        for (int j = 0; j < 6 * NM; ++j) {
            float a = fc1b[j];
            for (int m = 0; m < NM; ++m) a = fmaf(s[m], fc1w[j * NM + m], a);
            h[j] = fmaxf(a, 0.f);
        }
        for (int m = 0; m < NM; ++m) {
            float a = fc2b[m];
            for (int j = 0; j < 6 * NM; ++j) a = fmaf(h[j], fc2w[m * 6 * NM + j], a);
            ysh[m] = 1.f / (1.f + expf(-a));
        }
    }
    __syncthreads();
    for (int idx = threadIdx.x; idx < NM * NDIM * NDIM; idx += blockDim.x) {
        int o = idx & 127;
        int k = idx >> 7;      // m*128 + d
        int m = k >> 7;
        Wc[idx] = ysh[m] * cnnw[o * (NM * NDIM) + k];
    }
}

// ---------------------------------------------------------------- final GEMM with BN folded on A-load
// out[n,o] = cnnb[o] + sum_{m,d} relu((x2_m[n,d]-mu)*inv) * Wc[(m*128+d)*128+o]
// x2 for m=2 aliases `out` (raw agg); block reads its 16 rows before writing them.
__global__ void k_final(const float* __restrict__ x0, const float* __restrict__ x1,
                        const float* __restrict__ x2, const float* __restrict__ miA,
                        const float* __restrict__ Wc, const float* __restrict__ cnnb,
                        float* __restrict__ out) {
    __shared__ float arow[16][NM * NDIM + 1];
    int row0 = blockIdx.x * 16;
    for (int i = threadIdx.x; i < 16 * NM * NDIM; i += 256) {
        int rr = i / (NM * NDIM), kk = i - rr * (NM * NDIM);
        int m = kk >> 7, d = kk & 127;
        int g = row0 + rr;
        float v = 0.f;
        if (g < NN) {
            const float* src = (m == 0) ? x0 : (m == 1 ? x1 : x2);
            float raw = src[(size_t)g * NDIM + d];
            v = fmaxf((raw - miA[m * 256 + d]) * miA[m * 256 + 128 + d], 0.f);
        }
        arow[rr][kk] = v;
    }
    __syncthreads();
    int rrow = threadIdx.x >> 4;
    int o0 = (threadIdx.x & 15) * 8;
    float acc[8] = {0.f, 0.f, 0.f, 0.f, 0.f, 0.f, 0.f, 0.f};
#pragma unroll 4
    for (int k = 0; k < NM * NDIM; ++k) {
        float a = arow[rrow][k];
        const float4* wq = reinterpret_cast<const float4*>(Wc + k * NDIM + o0);
        float4 w0 = wq[0], w1 = wq[1];
        acc[0] = fmaf(a, w0.x, acc[0]); acc[1] = fmaf(a, w0.y, acc[1]);
        acc[2] = fmaf(a, w0.z, acc[2]); acc[3] = fmaf(a, w0.w, acc[3]);
        acc[4] = fmaf(a, w1.x, acc[4]); acc[5] = fmaf(a, w1.y, acc[5]);
        acc[6] = fmaf(a, w1.z, acc[6]); acc[7] = fmaf(a, w1.w, acc[7]);
    }
    int grow = row0 + rrow;
    if (grow < NN) {
        float4 r0 = {acc[0] + cnnb[o0],     acc[1] + cnnb[o0 + 1],
                     acc[2] + cnnb[o0 + 2], acc[3] + cnnb[o0 + 3]};
        float4 r1 = {acc[4] + cnnb[o0 + 4], acc[5] + cnnb[o0 + 5],
                     acc[6] + cnnb[o0 + 6], acc[7] + cnnb[o0 + 7]};
        float4* op = reinterpret_cast<float4*>(out + (size_t)grow * NDIM + o0);
        op[0] = r0; op[1] = r1;
    }
}

// ================================================================ launch
extern "C" void kernel_launch(void* const* d_in, const int* in_sizes, int n_in,
                              void* d_out, int out_size, void* d_ws, size_t ws_size,
                              hipStream_t stream) {
    const float* feat = (const float*)d_in[0];   // [3,50000,64]
    const int*   adj  = (const int*)d_in[1];     // [3,2,600000]
    const float* ew   = (const float*)d_in[2];   // [3,600000]
    const float* w1   = (const float*)d_in[3];   // [64,128]
    const float* w2   = (const float*)d_in[5];   // [128,128]
    const float* fc1w = (const float*)d_in[7];   // [18,3]
    const float* fc1b = (const float*)d_in[8];   // [18]
    const float* fc2w = (const float*)d_in[9];   // [3,18]
    const float* fc2b = (const float*)d_in[10];  // [3]
    const float* cnnw = (const float*)d_in[11];  // [128,3,128,1]
    const float* cnnb = (const float*)d_in[12];  // [128]
    float* out = (float*)d_out;

    float* ws = (float*)d_ws;
    size_t off = 0;
    float* bufA = ws + off; off += NTOT;   // GEMM output (XW)
    float* bufB = ws + off; off += NTOT;   // layer-1 aggregate
    float* x2b[NM];
    x2b[0] = ws + off; off += NTOT;
    x2b[1] = ws + off; off += NTOT;
    x2b[2] = out;                          // d_out doubles as branch-2 raw agg
    float* dis  = ws + off; off += NN;
    int*   cnt  = (int*)(ws + off); off += NN;        // count -> ticket counter
    int*   ptr  = (int*)(ws + off); off += NN + 2;    // CSR row pointers
    int*   bsum = (int*)(ws + off); off += 256;       // scan chunk totals
    float* stat = ws + off; off += 256;
    float* mi1  = ws + off; off += 256;
    float* mi2  = ws + off; off += NM * 256;
    float* ssum = ws + off; off += 4;
    float* Wc   = ws + off; off += NM * NDIM * NDIM;
    int2*  epack = (int2*)(ws + off); off += 2 * NE;  // (src,nrm) CSR-ordered

    const int EB = (NE + 255) / 256;

    k_fill<<<1, 64, 0, stream>>>(ssum, 0.f, 4);

    for (int m = 0; m < NM; ++m) {
        const float* fm   = feat + (size_t)m * NN * NF;
        const int*   rowp = adj + (size_t)m * 2 * NE;
        const int*   colp = rowp + NE;
        const float* ewm  = ew + (size_t)m * NE;
        float* x2 = x2b[m];

        // dis = rsqrt(1 + sum_in(ew)); in-degree counts; CSR
        k_fill<<<(NN + 255) / 256, 256, 0, stream>>>(dis, 1.0f, NN);
        k_fill<<<(NN + 255) / 256, 256, 0, stream>>>((float*)cnt, 0.f, NN);
        k_deg_count<<<EB, 256, 0, stream>>>(colp, ewm, dis, cnt);
        k_rsqrt<<<(NN + 255) / 256, 256, 0, stream>>>(dis, NN);
        k_scan1<<<NB_SCAN, 256, 0, stream>>>(cnt, ptr, bsum);
        k_scan2<<<1, 256, 0, stream>>>(bsum);
        k_scan3<<<NB_SCAN, 256, 0, stream>>>(ptr, bsum, cnt);
        k_fill_csr<<<EB, 256, 0, stream>>>(rowp, colp, ewm, dis, ptr, cnt, epack);

        // ---- layer 1: X@W1 -> gather -> stats (BN-apply folded into next GEMM)
        k_gemm<NF, false><<<NN / 16, 256, 0, stream>>>(fm, w1, nullptr, bufA);
        k_gather<<<NN / 2, 256, 0, stream>>>(bufA, dis, ptr, epack, bufB);
        k_fill<<<1, 256, 0, stream>>>(stat, 0.f, 256);
        k_bnstats<<<1024, 256, 0, stream>>>(bufB, stat);
        k_bnfinal<<<1, 128, 0, stream>>>(stat, mi1);

        // ---- layer 2: BN(relu)@W2 -> gather -> stats; SE sum read-only
        k_gemm<NDIM, true><<<NN / 16, 256, 0, stream>>>(bufB, w2, mi1, bufA);
        k_gather<<<NN / 2, 256, 0, stream>>>(bufA, dis, ptr, epack, x2);
        k_fill<<<1, 256, 0, stream>>>(stat, 0.f, 256);
        k_bnstats<<<1024, 256, 0, stream>>>(x2, stat);
        k_bnfinal<<<1, 128, 0, stream>>>(stat, mi2 + m * 256);
        k_bnsum<<<1024, 256, 0, stream>>>(x2, mi2 + m * 256, ssum + m);
    }

    // SE attention -> folded weight, then final [N,384]@[384,128] GEMM (BN on load)
    k_attn_wc<<<1, 256, 0, stream>>>(ssum, fc1w, fc1b, fc2w, fc2b, cnnw, Wc);
    k_final<<<NN / 16, 256, 0, stream>>>(x2b[0], x2b[1], x2b[2], mi2, Wc, cnnb, out);
}

// Round 3
// 1307.700 us; speedup vs baseline: 2.2137x; 1.5934x over previous
//
#include <hip/hip_runtime.h>

#define NN   50000      // nodes
#define NF   64         // input features
#define NDIM 128        // hidden / output dim
#define NE   600000     // edges
#define NM   3          // graphs
#define NTOT (NN * NDIM)
#define NB_SCAN 196     // ceil(NN/256)

// ---------------------------------------------------------------- utilities
__global__ void k_fill(float* __restrict__ p, float v, int n) {
    int i = blockIdx.x * blockDim.x + threadIdx.x;
    if (i < n) p[i] = v;
}

// dis = 1.0 (self-loop weight), cnt = 0
__global__ void k_init_dc(float* __restrict__ dis, int* __restrict__ cnt) {
    int i = blockIdx.x * blockDim.x + threadIdx.x;
    if (i < NN) { dis[i] = 1.0f; cnt[i] = 0; }
}

__global__ void k_deg_count(const int* __restrict__ col, const float* __restrict__ ew,
                            float* __restrict__ deg, int* __restrict__ cnt) {
    int e = blockIdx.x * blockDim.x + threadIdx.x;
    if (e < NE) {
        int c = col[e];
        atomicAdd(&deg[c], ew[e]);
        atomicAdd(&cnt[c], 1);
    }
}

// ---------------------------------------------------------------- CSR build (scan + ticket fill)
// also finalizes dis = rsqrt(deg) (deg atomics complete before this launch)
__global__ void k_scan1(const int* __restrict__ cnt, int* __restrict__ ptr,
                        int* __restrict__ bsum, float* __restrict__ dis) {
    __shared__ int s[256];
    int i = blockIdx.x * 256 + threadIdx.x;
    int v = (i < NN) ? cnt[i] : 0;
    if (i < NN) dis[i] = rsqrtf(dis[i]);
    s[threadIdx.x] = v;
    __syncthreads();
    for (int off = 1; off < 256; off <<= 1) {
        int x = (threadIdx.x >= off) ? s[threadIdx.x - off] : 0;
        __syncthreads();
        s[threadIdx.x] += x;
        __syncthreads();
    }
    if (i < NN) ptr[i] = s[threadIdx.x] - v;           // chunk-local exclusive
    if (threadIdx.x == 255) bsum[blockIdx.x] = s[255]; // chunk total
}

__global__ void k_scan2(int* __restrict__ bsum) {       // exclusive scan of chunk totals
    __shared__ int s[256];
    int t = threadIdx.x;
    int v = (t < NB_SCAN) ? bsum[t] : 0;
    s[t] = v;
    __syncthreads();
    for (int off = 1; off < 256; off <<= 1) {
        int x = (t >= off) ? s[t - off] : 0;
        __syncthreads();
        s[t] += x;
        __syncthreads();
    }
    bsum[t] = s[t] - v;
}

__global__ void k_scan3(int* __restrict__ ptr, const int* __restrict__ bsum,
                        int* __restrict__ cnt) {
    int i = blockIdx.x * 256 + threadIdx.x;
    if (i < NN) {
        ptr[i] += bsum[i >> 8];
        cnt[i] = 0;                                    // becomes the ticket counter
    }
    if (i == 0) ptr[NN] = NE;
}

// epack[j] = (src_row, bitcast(norm)) in CSR-by-col order
__global__ void k_fill_csr(const int* __restrict__ row, const int* __restrict__ col,
                           const float* __restrict__ ew, const float* __restrict__ dis,
                           const int* __restrict__ ptr, int* __restrict__ fill,
                           int2* __restrict__ epack) {
    int e = blockIdx.x * blockDim.x + threadIdx.x;
    if (e >= NE) return;
    int r = row[e], c = col[e];
    int slot = atomicAdd(&fill[c], 1);
    float nrm = dis[r] * ew[e] * dis[c];
    epack[ptr[c] + slot] = make_int2(r, __float_as_int(nrm));
}

// ---------------------------------------------------------------- LDS-tiled GEMM
// out[n,o] = sum_k A[n,k]*W[k,o], W staged in LDS per KC=64 chunk.
// 64 rows x 128 cols per block; 256 thr = 16 rgroups(4 rows) x 16 cgroups(8 cols).
// BN: A elements get relu((a-mu)*inv) on LDS load (only used with K=128).
template<int K, bool BN>
__global__ void k_gemm_t(const float* __restrict__ A, const float* __restrict__ W,
                         const float* __restrict__ mi, float* __restrict__ out) {
    __shared__ float sA[64][65];
    __shared__ float sW[64][128];
    const int row0 = blockIdx.x * 64;
    const int tid = threadIdx.x;
    const int r0 = (tid >> 4) * 4;
    const int c0 = (tid & 15) * 8;
    float acc[4][8];
#pragma unroll
    for (int i = 0; i < 4; ++i)
#pragma unroll
        for (int j = 0; j < 8; ++j) acc[i][j] = 0.f;

    for (int ch = 0; ch < K / 64; ++ch) {
        const int kc0 = ch * 64;
        // stage A chunk [64 rows][64 k]
        for (int i = tid; i < 64 * 64; i += 256) {
            int rr = i >> 6, kk = i & 63;
            int g = row0 + rr;
            float v = (g < NN) ? A[(size_t)g * K + kc0 + kk] : 0.f;
            if (BN) v = fmaxf((v - mi[kc0 + kk]) * mi[128 + kc0 + kk], 0.f);
            sA[rr][kk] = v;
        }
        // stage W chunk [64 k][128]
        for (int i = tid; i < 64 * 128; i += 256) {
            int kk = i >> 7, c = i & 127;
            sW[kk][c] = W[(size_t)(kc0 + kk) * NDIM + c];
        }
        __syncthreads();
#pragma unroll 4
        for (int k = 0; k < 64; ++k) {
            float a0 = sA[r0 + 0][k], a1 = sA[r0 + 1][k];
            float a2 = sA[r0 + 2][k], a3 = sA[r0 + 3][k];
            float4 w0 = *reinterpret_cast<const float4*>(&sW[k][c0]);
            float4 w1 = *reinterpret_cast<const float4*>(&sW[k][c0 + 4]);
            acc[0][0] = fmaf(a0, w0.x, acc[0][0]); acc[0][1] = fmaf(a0, w0.y, acc[0][1]);
            acc[0][2] = fmaf(a0, w0.z, acc[0][2]); acc[0][3] = fmaf(a0, w0.w, acc[0][3]);
            acc[0][4] = fmaf(a0, w1.x, acc[0][4]); acc[0][5] = fmaf(a0, w1.y, acc[0][5]);
            acc[0][6] = fmaf(a0, w1.z, acc[0][6]); acc[0][7] = fmaf(a0, w1.w, acc[0][7]);
            acc[1][0] = fmaf(a1, w0.x, acc[1][0]); acc[1][1] = fmaf(a1, w0.y, acc[1][1]);
            acc[1][2] = fmaf(a1, w0.z, acc[1][2]); acc[1][3] = fmaf(a1, w0.w, acc[1][3]);
            acc[1][4] = fmaf(a1, w1.x, acc[1][4]); acc[1][5] = fmaf(a1, w1.y, acc[1][5]);
            acc[1][6] = fmaf(a1, w1.z, acc[1][6]); acc[1][7] = fmaf(a1, w1.w, acc[1][7]);
            acc[2][0] = fmaf(a2, w0.x, acc[2][0]); acc[2][1] = fmaf(a2, w0.y, acc[2][1]);
            acc[2][2] = fmaf(a2, w0.z, acc[2][2]); acc[2][3] = fmaf(a2, w0.w, acc[2][3]);
            acc[2][4] = fmaf(a2, w1.x, acc[2][4]); acc[2][5] = fmaf(a2, w1.y, acc[2][5]);
            acc[2][6] = fmaf(a2, w1.z, acc[2][6]); acc[2][7] = fmaf(a2, w1.w, acc[2][7]);
            acc[3][0] = fmaf(a3, w0.x, acc[3][0]); acc[3][1] = fmaf(a3, w0.y, acc[3][1]);
            acc[3][2] = fmaf(a3, w0.z, acc[3][2]); acc[3][3] = fmaf(a3, w0.w, acc[3][3]);
            acc[3][4] = fmaf(a3, w1.x, acc[3][4]); acc[3][5] = fmaf(a3, w1.y, acc[3][5]);
            acc[3][6] = fmaf(a3, w1.z, acc[3][6]); acc[3][7] = fmaf(a3, w1.w, acc[3][7]);
        }
        __syncthreads();
    }
#pragma unroll
    for (int i = 0; i < 4; ++i) {
        int grow = row0 + r0 + i;
        if (grow < NN) {
            float4 v0 = {acc[i][0], acc[i][1], acc[i][2], acc[i][3]};
            float4 v1 = {acc[i][4], acc[i][5], acc[i][6], acc[i][7]};
            float4* op = reinterpret_cast<float4*>(out + (size_t)grow * NDIM + c0);
            op[0] = v0; op[1] = v1;
        }
    }
}

// ---------------------------------------------------------------- CSR gather aggregation
// out[c,:] = xw[c,:]*dis[c]^2 + sum_j xw[src_j,:]*nrm_j
// 32 lanes/node (float4/lane), 8 nodes/block, 2-way ILP, no atomics.
__global__ void k_gather(const float* __restrict__ xw, const float* __restrict__ dis,
                         const int* __restrict__ ptr, const int2* __restrict__ epack,
                         float* __restrict__ out) {
    int sub = threadIdx.x >> 5;
    int lane = threadIdx.x & 31;
    int c = blockIdx.x * 8 + sub;
    const float4* xq = reinterpret_cast<const float4*>(xw);
    float ds = dis[c];
    float s2 = ds * ds;
    float4 self = xq[(size_t)c * 32 + lane];
    float4 a0 = {self.x * s2, self.y * s2, self.z * s2, self.w * s2};
    float4 a1 = {0.f, 0.f, 0.f, 0.f};
    int j = ptr[c], j1 = ptr[c + 1];
    for (; j + 1 < j1; j += 2) {
        int2 e0 = epack[j], e1 = epack[j + 1];
        float4 r0 = xq[(size_t)e0.x * 32 + lane];
        float4 r1 = xq[(size_t)e1.x * 32 + lane];
        float n0 = __int_as_float(e0.y), n1 = __int_as_float(e1.y);
        a0.x = fmaf(r0.x, n0, a0.x); a0.y = fmaf(r0.y, n0, a0.y);
        a0.z = fmaf(r0.z, n0, a0.z); a0.w = fmaf(r0.w, n0, a0.w);
        a1.x = fmaf(r1.x, n1, a1.x); a1.y = fmaf(r1.y, n1, a1.y);
        a1.z = fmaf(r1.z, n1, a1.z); a1.w = fmaf(r1.w, n1, a1.w);
    }
    if (j < j1) {
        int2 e0 = epack[j];
        float4 r0 = xq[(size_t)e0.x * 32 + lane];
        float n0 = __int_as_float(e0.y);
        a0.x = fmaf(r0.x, n0, a0.x); a0.y = fmaf(r0.y, n0, a0.y);
        a0.z = fmaf(r0.z, n0, a0.z); a0.w = fmaf(r0.w, n0, a0.w);
    }
    float4 res = {a0.x + a1.x, a0.y + a1.y, a0.z + a1.z, a0.w + a1.w};
    reinterpret_cast<float4*>(out)[(size_t)c * 32 + lane] = res;
}

// ---------------------------------------------------------------- BatchNorm stats
__global__ void k_bnstats(const float* __restrict__ x, float* __restrict__ stat) {
    int d = threadIdx.x & 127;
    int sub = threadIdx.x >> 7;
    float s = 0.f, s2 = 0.f;
    for (int n = blockIdx.x * 2 + sub; n < NN; n += gridDim.x * 2) {
        float v = x[(size_t)n * NDIM + d];
        s += v;
        s2 = fmaf(v, v, s2);
    }
    __shared__ float red[256];
    red[threadIdx.x] = s;
    __syncthreads();
    if (threadIdx.x < 128) atomicAdd(&stat[threadIdx.x], red[threadIdx.x] + red[threadIdx.x + 128]);
    __syncthreads();
    red[threadIdx.x] = s2;
    __syncthreads();
    if (threadIdx.x < 128) atomicAdd(&stat[128 + threadIdx.x], red[threadIdx.x] + red[threadIdx.x + 128]);
}

__global__ void k_bnfinal(const float* __restrict__ stat, float* __restrict__ mi) {
    int d = threadIdx.x;   // 128 threads
    float m = stat[d] * (1.f / (float)NN);
    float v = stat[128 + d] * (1.f / (float)NN) - m * m;  // biased var (torch BN)
    mi[d] = m;
    mi[128 + d] = rsqrtf(v + 1e-5f);
}

// sum of relu((x-mu)*inv) over everything, WITHOUT writing x (x stays raw)
__global__ void k_bnsum(const float* __restrict__ x, const float* __restrict__ mi,
                        float* __restrict__ ssum) {
    __shared__ float red[256];
    float local = 0.f;
    for (int i = blockIdx.x * blockDim.x + threadIdx.x; i < NTOT;
         i += gridDim.x * blockDim.x) {
        int d = i & 127;
        local += fmaxf((x[i] - mi[d]) * mi[128 + d], 0.f);
    }
    red[threadIdx.x] = local;
    __syncthreads();
    for (int s = 128; s > 0; s >>= 1) {
        if (threadIdx.x < s) red[threadIdx.x] += red[threadIdx.x + s];
        __syncthreads();
    }
    if (threadIdx.x == 0) atomicAdd(ssum, red[0]);
}

// ---------------------------------------------------------------- SE attention -> folded conv weight
__global__ void k_attn_wc(const float* __restrict__ ssum, const float* __restrict__ fc1w,
                          const float* __restrict__ fc1b, const float* __restrict__ fc2w,
                          const float* __restrict__ fc2b, const float* __restrict__ cnnw,
                          float* __restrict__ Wc) {
    __shared__ float ysh[NM];
    if (threadIdx.x == 0) {
        float s[NM], h[6 * NM];
        for (int m = 0; m < NM; ++m) s[m] = ssum[m] * (1.f / (float)NTOT);
        for (int j = 0; j < 6 * NM; ++j) {
            float a = fc1b[j];
            for (int m = 0; m < NM; ++m) a = fmaf(s[m], fc1w[j * NM + m], a);
            h[j] = fmaxf(a, 0.f);
        }
        for (int m = 0; m < NM; ++m) {
            float a = fc2b[m];
            for (int j = 0; j < 6 * NM; ++j) a = fmaf(h[j], fc2w[m * 6 * NM + j], a);
            ysh[m] = 1.f / (1.f + expf(-a));
        }
    }
    __syncthreads();
    for (int idx = threadIdx.x; idx < NM * NDIM * NDIM; idx += blockDim.x) {
        int o = idx & 127;
        int k = idx >> 7;      // m*128 + d
        int m = k >> 7;
        Wc[idx] = ysh[m] * cnnw[o * (NM * NDIM) + k];
    }
}

// ---------------------------------------------------------------- final GEMM (K=384), BN folded on A-load
// x2 for m=2 aliases `out`: every block reads only its own 64 rows (k-loop)
// before writing them (epilogue) -> safe.
__global__ void k_final_t(const float* __restrict__ x0, const float* __restrict__ x1,
                          const float* __restrict__ x2, const float* __restrict__ miA,
                          const float* __restrict__ Wc, const float* __restrict__ cnnb,
                          float* __restrict__ out) {
    __shared__ float sA[64][65];
    __shared__ float sW[64][128];
    const int row0 = blockIdx.x * 64;
    const int tid = threadIdx.x;
    const int r0 = (tid >> 4) * 4;
    const int c0 = (tid & 15) * 8;
    float acc[4][8];
#pragma unroll
    for (int i = 0; i < 4; ++i)
#pragma unroll
        for (int j = 0; j < 8; ++j) acc[i][j] = 0.f;

#pragma unroll
    for (int ch = 0; ch < 6; ++ch) {
        const int kc0 = ch * 64;
        const int m = ch >> 1;
        const int dbase = (ch & 1) * 64;
        const float* src = (m == 0) ? x0 : (m == 1 ? x1 : x2);
        for (int i = tid; i < 64 * 64; i += 256) {
            int rr = i >> 6, kk = i & 63;
            int g = row0 + rr;
            float v = 0.f;
            if (g < NN) {
                float raw = src[(size_t)g * NDIM + dbase + kk];
                v = fmaxf((raw - miA[m * 256 + dbase + kk]) * miA[m * 256 + 128 + dbase + kk], 0.f);
            }
            sA[rr][kk] = v;
        }
        for (int i = tid; i < 64 * 128; i += 256) {
            int kk = i >> 7, c = i & 127;
            sW[kk][c] = Wc[(size_t)(kc0 + kk) * NDIM + c];
        }
        __syncthreads();
#pragma unroll 4
        for (int k = 0; k < 64; ++k) {
            float a0 = sA[r0 + 0][k], a1 = sA[r0 + 1][k];
            float a2 = sA[r0 + 2][k], a3 = sA[r0 + 3][k];
            float4 w0 = *reinterpret_cast<const float4*>(&sW[k][c0]);
            float4 w1 = *reinterpret_cast<const float4*>(&sW[k][c0 + 4]);
            acc[0][0] = fmaf(a0, w0.x, acc[0][0]); acc[0][1] = fmaf(a0, w0.y, acc[0][1]);
            acc[0][2] = fmaf(a0, w0.z, acc[0][2]); acc[0][3] = fmaf(a0, w0.w, acc[0][3]);
            acc[0][4] = fmaf(a0, w1.x, acc[0][4]); acc[0][5] = fmaf(a0, w1.y, acc[0][5]);
            acc[0][6] = fmaf(a0, w1.z, acc[0][6]); acc[0][7] = fmaf(a0, w1.w, acc[0][7]);
            acc[1][0] = fmaf(a1, w0.x, acc[1][0]); acc[1][1] = fmaf(a1, w0.y, acc[1][1]);
            acc[1][2] = fmaf(a1, w0.z, acc[1][2]); acc[1][3] = fmaf(a1, w0.w, acc[1][3]);
            acc[1][4] = fmaf(a1, w1.x, acc[1][4]); acc[1][5] = fmaf(a1, w1.y, acc[1][5]);
            acc[1][6] = fmaf(a1, w1.z, acc[1][6]); acc[1][7] = fmaf(a1, w1.w, acc[1][7]);
            acc[2][0] = fmaf(a2, w0.x, acc[2][0]); acc[2][1] = fmaf(a2, w0.y, acc[2][1]);
            acc[2][2] = fmaf(a2, w0.z, acc[2][2]); acc[2][3] = fmaf(a2, w0.w, acc[2][3]);
            acc[2][4] = fmaf(a2, w1.x, acc[2][4]); acc[2][5] = fmaf(a2, w1.y, acc[2][5]);
            acc[2][6] = fmaf(a2, w1.z, acc[2][6]); acc[2][7] = fmaf(a2, w1.w, acc[2][7]);
            acc[3][0] = fmaf(a3, w0.x, acc[3][0]); acc[3][1] = fmaf(a3, w0.y, acc[3][1]);
            acc[3][2] = fmaf(a3, w0.z, acc[3][2]); acc[3][3] = fmaf(a3, w0.w, acc[3][3]);
            acc[3][4] = fmaf(a3, w1.x, acc[3][4]); acc[3][5] = fmaf(a3, w1.y, acc[3][5]);
            acc[3][6] = fmaf(a3, w1.z, acc[3][6]); acc[3][7] = fmaf(a3, w1.w, acc[3][7]);
        }
        __syncthreads();
    }
#pragma unroll
    for (int i = 0; i < 4; ++i) {
        int grow = row0 + r0 + i;
        if (grow < NN) {
            float4 v0 = {acc[i][0] + cnnb[c0],     acc[i][1] + cnnb[c0 + 1],
                         acc[i][2] + cnnb[c0 + 2], acc[i][3] + cnnb[c0 + 3]};
            float4 v1 = {acc[i][4] + cnnb[c0 + 4], acc[i][5] + cnnb[c0 + 5],
                         acc[i][6] + cnnb[c0 + 6], acc[i][7] + cnnb[c0 + 7]};
            float4* op = reinterpret_cast<float4*>(out + (size_t)grow * NDIM + c0);
            op[0] = v0; op[1] = v1;
        }
    }
}

// ================================================================ launch
extern "C" void kernel_launch(void* const* d_in, const int* in_sizes, int n_in,
                              void* d_out, int out_size, void* d_ws, size_t ws_size,
                              hipStream_t stream) {
    const float* feat = (const float*)d_in[0];   // [3,50000,64]
    const int*   adj  = (const int*)d_in[1];     // [3,2,600000]
    const float* ew   = (const float*)d_in[2];   // [3,600000]
    const float* w1   = (const float*)d_in[3];   // [64,128]
    const float* w2   = (const float*)d_in[5];   // [128,128]
    const float* fc1w = (const float*)d_in[7];   // [18,3]
    const float* fc1b = (const float*)d_in[8];   // [18]
    const float* fc2w = (const float*)d_in[9];   // [3,18]
    const float* fc2b = (const float*)d_in[10];  // [3]
    const float* cnnw = (const float*)d_in[11];  // [128,3,128,1]
    const float* cnnb = (const float*)d_in[12];  // [128]
    float* out = (float*)d_out;

    float* ws = (float*)d_ws;
    size_t off = 0;
    float* bufA = ws + off; off += NTOT;   // GEMM output (XW)
    float* bufB = ws + off; off += NTOT;   // layer-1 aggregate
    float* x2b[NM];
    x2b[0] = ws + off; off += NTOT;
    x2b[1] = ws + off; off += NTOT;
    x2b[2] = out;                          // d_out doubles as branch-2 raw agg
    float* dis  = ws + off; off += NN;
    int*   cnt  = (int*)(ws + off); off += NN;        // count -> ticket counter
    int*   ptr  = (int*)(ws + off); off += NN + 2;    // CSR row pointers
    int*   bsum = (int*)(ws + off); off += 256;       // scan chunk totals
    float* stat6 = ws + off; off += 6 * 256;          // one stat buffer per use
    float* ssum = ws + off; off += 4;                 // (contiguous w/ stat6)
    float* mi1  = ws + off; off += 256;
    float* mi2  = ws + off; off += NM * 256;
    float* Wc   = ws + off; off += NM * NDIM * NDIM;
    int2*  epack = (int2*)(ws + off); off += 2 * NE;  // (src,nrm) CSR-ordered

    const int EB = (NE + 255) / 256;
    const int GB = (NN + 63) / 64;   // GEMM blocks

    // zero all 6 stat buffers + ssum once
    k_fill<<<(6 * 256 + 4 + 255) / 256, 256, 0, stream>>>(stat6, 0.f, 6 * 256 + 4);

    for (int m = 0; m < NM; ++m) {
        const float* fm   = feat + (size_t)m * NN * NF;
        const int*   rowp = adj + (size_t)m * 2 * NE;
        const int*   colp = rowp + NE;
        const float* ewm  = ew + (size_t)m * NE;
        float* x2 = x2b[m];
        float* st1 = stat6 + (m * 2 + 0) * 256;
        float* st2 = stat6 + (m * 2 + 1) * 256;

        // dis/cnt init -> degree+count -> rsqrt(in scan1) -> CSR
        k_init_dc<<<NB_SCAN, 256, 0, stream>>>(dis, cnt);
        k_deg_count<<<EB, 256, 0, stream>>>(colp, ewm, dis, cnt);
        k_scan1<<<NB_SCAN, 256, 0, stream>>>(cnt, ptr, bsum, dis);
        k_scan2<<<1, 256, 0, stream>>>(bsum);
        k_scan3<<<NB_SCAN, 256, 0, stream>>>(ptr, bsum, cnt);
        k_fill_csr<<<EB, 256, 0, stream>>>(rowp, colp, ewm, dis, ptr, cnt, epack);

        // ---- layer 1: X@W1 -> gather -> stats (BN-apply folded into next GEMM)
        k_gemm_t<NF, false><<<GB, 256, 0, stream>>>(fm, w1, nullptr, bufA);
        k_gather<<<NN / 8, 256, 0, stream>>>(bufA, dis, ptr, epack, bufB);
        k_bnstats<<<1024, 256, 0, stream>>>(bufB, st1);
        k_bnfinal<<<1, 128, 0, stream>>>(st1, mi1);

        // ---- layer 2: BN(relu)@W2 -> gather -> stats; SE sum read-only
        k_gemm_t<NDIM, true><<<GB, 256, 0, stream>>>(bufB, w2, mi1, bufA);
        k_gather<<<NN / 8, 256, 0, stream>>>(bufA, dis, ptr, epack, x2);
        k_bnstats<<<1024, 256, 0, stream>>>(x2, st2);
        k_bnfinal<<<1, 128, 0, stream>>>(st2, mi2 + m * 256);
        k_bnsum<<<1024, 256, 0, stream>>>(x2, mi2 + m * 256, ssum + m);
    }

    // SE attention -> folded weight, then final [N,384]@[384,128] GEMM (BN on load)
    k_attn_wc<<<1, 256, 0, stream>>>(ssum, fc1w, fc1b, fc2w, fc2b, cnnw, Wc);
    k_final_t<<<GB, 256, 0, stream>>>(x2b[0], x2b[1], x2b[2], mi2, Wc, cnnb, out);
}

// Round 4
// 996.218 us; speedup vs baseline: 2.9059x; 1.3127x over previous
//
#include <hip/hip_runtime.h>

#define NN   50000      // nodes
#define NF   64         // input features
#define NDIM 128        // hidden / output dim
#define NE   600000     // edges
#define NM   3          // graphs
#define NTOT (NN * NDIM)
#define NB_SCAN 196     // ceil(NN/256)

typedef __attribute__((ext_vector_type(8))) short short8;
typedef __attribute__((ext_vector_type(4))) float f32x4;

__device__ __forceinline__ unsigned short f2bf(float x) {
    unsigned int u = __float_as_uint(x);
    return (unsigned short)((u + 0x7FFFu + ((u >> 16) & 1u)) >> 16);  // RNE
}
__device__ __forceinline__ float blo(unsigned int u) { return __uint_as_float(u << 16); }
__device__ __forceinline__ float bhi(unsigned int u) { return __uint_as_float(u & 0xFFFF0000u); }

// ---------------------------------------------------------------- utilities
__global__ void k_fill(float* __restrict__ p, float v, int n) {
    int i = blockIdx.x * blockDim.x + threadIdx.x;
    if (i < n) p[i] = v;
}

__global__ void k_init_dc(float* __restrict__ dis, int* __restrict__ cnt) {
    int i = blockIdx.x * blockDim.x + threadIdx.x;
    if (i < NN) { dis[i] = 1.0f; cnt[i] = 0; }
}

__global__ void k_deg_count(const int* __restrict__ col, const float* __restrict__ ew,
                            float* __restrict__ deg, int* __restrict__ cnt) {
    int e = blockIdx.x * blockDim.x + threadIdx.x;
    if (e < NE) {
        int c = col[e];
        atomicAdd(&deg[c], ew[e]);
        atomicAdd(&cnt[c], 1);
    }
}

// W1t[n][k] = bf16(W1[k][n]) (128x64), W2t[n][k] = bf16(W2[k][n]) (128x128)
__global__ void k_prepw(const float* __restrict__ w1, const float* __restrict__ w2,
                        unsigned short* __restrict__ w1t, unsigned short* __restrict__ w2t) {
    int i = blockIdx.x * 256 + threadIdx.x;
    if (i < 128 * 64) {
        int n = i >> 6, k = i & 63;
        w1t[i] = f2bf(w1[k * 128 + n]);
    } else if (i < 128 * 64 + 128 * 128) {
        int j = i - 128 * 64;
        int n = j >> 7, k = j & 127;
        w2t[j] = f2bf(w2[k * 128 + n]);
    }
}

// ---------------------------------------------------------------- CSR build
__global__ void k_scan1(const int* __restrict__ cnt, int* __restrict__ ptr,
                        int* __restrict__ bsum, float* __restrict__ dis) {
    __shared__ int s[256];
    int i = blockIdx.x * 256 + threadIdx.x;
    int v = (i < NN) ? cnt[i] : 0;
    if (i < NN) dis[i] = rsqrtf(dis[i]);
    s[threadIdx.x] = v;
    __syncthreads();
    for (int off = 1; off < 256; off <<= 1) {
        int x = (threadIdx.x >= off) ? s[threadIdx.x - off] : 0;
        __syncthreads();
        s[threadIdx.x] += x;
        __syncthreads();
    }
    if (i < NN) ptr[i] = s[threadIdx.x] - v;
    if (threadIdx.x == 255) bsum[blockIdx.x] = s[255];
}

__global__ void k_scan2(int* __restrict__ bsum) {
    __shared__ int s[256];
    int t = threadIdx.x;
    int v = (t < NB_SCAN) ? bsum[t] : 0;
    s[t] = v;
    __syncthreads();
    for (int off = 1; off < 256; off <<= 1) {
        int x = (t >= off) ? s[t - off] : 0;
        __syncthreads();
        s[t] += x;
        __syncthreads();
    }
    bsum[t] = s[t] - v;
}

__global__ void k_scan3(int* __restrict__ ptr, const int* __restrict__ bsum,
                        int* __restrict__ cnt) {
    int i = blockIdx.x * 256 + threadIdx.x;
    if (i < NN) {
        ptr[i] += bsum[i >> 8];
        cnt[i] = 0;
    }
    if (i == 0) ptr[NN] = NE;
}

__global__ void k_fill_csr(const int* __restrict__ row, const int* __restrict__ col,
                           const float* __restrict__ ew, const float* __restrict__ dis,
                           const int* __restrict__ ptr, int* __restrict__ fill,
                           int2* __restrict__ epack) {
    int e = blockIdx.x * blockDim.x + threadIdx.x;
    if (e >= NE) return;
    int r = row[e], c = col[e];
    int slot = atomicAdd(&fill[c], 1);
    float nrm = dis[r] * ew[e] * dis[c];
    epack[ptr[c] + slot] = make_int2(r, __float_as_int(nrm));
}

// ---------------------------------------------------------------- MFMA GEMM (bf16 in, f32 acc)
// out_bf[n,o] = bf16( sum_k A[n,k]*W[k,o] ); A f32 (+opt BN fold), Wt bf16 [N=128][K].
// 128 rows/block, 4 waves x 32 rows, full 128 cols per wave.
// LDS rows padded to 72 bf16 (144B) -> 16B-aligned frags, 2-way bank alias (free).
template<int K, bool BN>
__global__ __launch_bounds__(256, 2) void k_mgemm(const float* __restrict__ A,
                                                  const unsigned short* __restrict__ Wt,
                                                  const float* __restrict__ mi,
                                                  unsigned short* __restrict__ outb) {
    __shared__ unsigned short sA[128 * 72];
    __shared__ unsigned short sB[128 * 72];
    const int tid = threadIdx.x;
    const int lane = tid & 63, wave = tid >> 6;
    const int llo = lane & 15, lhi = lane >> 4;
    const int row0 = blockIdx.x * 128;
    const int waveR0 = wave * 32;
    const unsigned int* Wtu = reinterpret_cast<const unsigned int*>(Wt);
    f32x4 acc[2][8];
#pragma unroll
    for (int i = 0; i < 2; ++i)
#pragma unroll
        for (int t = 0; t < 8; ++t) acc[i][t] = (f32x4){0.f, 0.f, 0.f, 0.f};

    for (int ch = 0; ch < K / 64; ++ch) {
        const int kc0 = ch * 64;
        // stage A chunk [128 rows][64 k] as bf16 pairs
        for (int idx = tid; idx < 4096; idx += 256) {
            int r = idx >> 5, kk2 = idx & 31;
            int g = row0 + r;
            float vx = 0.f, vy = 0.f;
            if (g < NN) {
                float2 v = *reinterpret_cast<const float2*>(A + (size_t)g * K + kc0 + kk2 * 2);
                vx = v.x; vy = v.y;
                if (BN) {
                    int d0 = kc0 + kk2 * 2;
                    vx = fmaxf((vx - mi[d0]) * mi[128 + d0], 0.f);
                    vy = fmaxf((vy - mi[d0 + 1]) * mi[128 + d0 + 1], 0.f);
                }
            }
            reinterpret_cast<unsigned int*>(sA)[r * 36 + kk2] =
                (unsigned int)f2bf(vx) | ((unsigned int)f2bf(vy) << 16);
        }
        // stage Wt chunk [128 n][64 k]
        for (int idx = tid; idx < 4096; idx += 256) {
            int n = idx >> 5, kk2 = idx & 31;
            reinterpret_cast<unsigned int*>(sB)[n * 36 + kk2] =
                Wtu[n * (K / 2) + kc0 / 2 + kk2];
        }
        __syncthreads();
#pragma unroll
        for (int ks = 0; ks < 64; ks += 32) {
            short8 a0 = *reinterpret_cast<const short8*>(sA + (waveR0 + llo) * 72 + ks + lhi * 8);
            short8 a1 = *reinterpret_cast<const short8*>(sA + (waveR0 + 16 + llo) * 72 + ks + lhi * 8);
#pragma unroll
            for (int t = 0; t < 8; ++t) {
                short8 b = *reinterpret_cast<const short8*>(sB + (t * 16 + llo) * 72 + ks + lhi * 8);
                acc[0][t] = __builtin_amdgcn_mfma_f32_16x16x32_bf16(a0, b, acc[0][t], 0, 0, 0);
                acc[1][t] = __builtin_amdgcn_mfma_f32_16x16x32_bf16(a1, b, acc[1][t], 0, 0, 0);
            }
        }
        __syncthreads();
    }
#pragma unroll
    for (int rt = 0; rt < 2; ++rt)
#pragma unroll
        for (int r = 0; r < 4; ++r) {
            int grow = row0 + waveR0 + rt * 16 + lhi * 4 + r;
            if (grow < NN) {
#pragma unroll
                for (int t = 0; t < 8; ++t)
                    outb[(size_t)grow * NDIM + t * 16 + llo] = f2bf(acc[rt][t][r]);
            }
        }
}

// ---------------------------------------------------------------- final MFMA GEMM (K=384, 3 srcs, BN fold, +bias)
// x2 (m=2) aliases `out`: each block reads only its own 128 rows (all staging
// completes before the epilogue barrier) then writes the same rows.
__global__ __launch_bounds__(256, 2) void k_mfinal(const float* __restrict__ x0,
                                                   const float* __restrict__ x1,
                                                   const float* __restrict__ x2,
                                                   const float* __restrict__ miA,
                                                   const unsigned short* __restrict__ WcT,
                                                   const float* __restrict__ cnnb,
                                                   float* __restrict__ out) {
    __shared__ unsigned short sA[128 * 72];
    __shared__ unsigned short sB[128 * 72];
    const int tid = threadIdx.x;
    const int lane = tid & 63, wave = tid >> 6;
    const int llo = lane & 15, lhi = lane >> 4;
    const int row0 = blockIdx.x * 128;
    const int waveR0 = wave * 32;
    const unsigned int* Wtu = reinterpret_cast<const unsigned int*>(WcT);
    f32x4 acc[2][8];
#pragma unroll
    for (int i = 0; i < 2; ++i)
#pragma unroll
        for (int t = 0; t < 8; ++t) acc[i][t] = (f32x4){0.f, 0.f, 0.f, 0.f};

#pragma unroll
    for (int ch = 0; ch < 6; ++ch) {
        const int m = ch >> 1;
        const int dbase = (ch & 1) * 64;
        const float* src = (m == 0) ? x0 : (m == 1 ? x1 : x2);
        for (int idx = tid; idx < 4096; idx += 256) {
            int r = idx >> 5, kk2 = idx & 31;
            int g = row0 + r;
            float vx = 0.f, vy = 0.f;
            if (g < NN) {
                float2 v = *reinterpret_cast<const float2*>(src + (size_t)g * NDIM + dbase + kk2 * 2);
                int d0 = m * 256 + dbase + kk2 * 2;
                vx = fmaxf((v.x - miA[d0]) * miA[d0 + 128], 0.f);
                vy = fmaxf((v.y - miA[d0 + 1]) * miA[d0 + 129], 0.f);
            }
            reinterpret_cast<unsigned int*>(sA)[r * 36 + kk2] =
                (unsigned int)f2bf(vx) | ((unsigned int)f2bf(vy) << 16);
        }
        for (int idx = tid; idx < 4096; idx += 256) {
            int n = idx >> 5, kk2 = idx & 31;
            reinterpret_cast<unsigned int*>(sB)[n * 36 + kk2] = Wtu[n * 192 + ch * 32 + kk2];
        }
        __syncthreads();
#pragma unroll
        for (int ks = 0; ks < 64; ks += 32) {
            short8 a0 = *reinterpret_cast<const short8*>(sA + (waveR0 + llo) * 72 + ks + lhi * 8);
            short8 a1 = *reinterpret_cast<const short8*>(sA + (waveR0 + 16 + llo) * 72 + ks + lhi * 8);
#pragma unroll
            for (int t = 0; t < 8; ++t) {
                short8 b = *reinterpret_cast<const short8*>(sB + (t * 16 + llo) * 72 + ks + lhi * 8);
                acc[0][t] = __builtin_amdgcn_mfma_f32_16x16x32_bf16(a0, b, acc[0][t], 0, 0, 0);
                acc[1][t] = __builtin_amdgcn_mfma_f32_16x16x32_bf16(a1, b, acc[1][t], 0, 0, 0);
            }
        }
        __syncthreads();
    }
#pragma unroll
    for (int rt = 0; rt < 2; ++rt)
#pragma unroll
        for (int r = 0; r < 4; ++r) {
            int grow = row0 + waveR0 + rt * 16 + lhi * 4 + r;
            if (grow < NN) {
#pragma unroll
                for (int t = 0; t < 8; ++t)
                    out[(size_t)grow * NDIM + t * 16 + llo] = acc[rt][t][r] + cnnb[t * 16 + llo];
            }
        }
}

// ---------------------------------------------------------------- CSR gather (bf16 rows, f32 acc)
// out[c,:] = xw[c,:]*dis[c]^2 + sum_j xw[src_j,:]*nrm_j ; 32 lanes/node (4 bf16/lane).
__global__ void k_gather(const unsigned short* __restrict__ xwb, const float* __restrict__ dis,
                         const int* __restrict__ ptr, const int2* __restrict__ epack,
                         float* __restrict__ outf) {
    int sub = threadIdx.x >> 5;
    int lane = threadIdx.x & 31;
    int c = blockIdx.x * 8 + sub;
    const uint2* xq = reinterpret_cast<const uint2*>(xwb);
    float ds = dis[c];
    float s2 = ds * ds;
    uint2 sv = xq[(size_t)c * 32 + lane];
    float a0 = blo(sv.x) * s2, a1 = bhi(sv.x) * s2;
    float a2 = blo(sv.y) * s2, a3 = bhi(sv.y) * s2;
    float b0 = 0.f, b1 = 0.f, b2 = 0.f, b3 = 0.f;
    int j = ptr[c], j1 = ptr[c + 1];
    for (; j + 1 < j1; j += 2) {
        int2 e0 = epack[j], e1 = epack[j + 1];
        uint2 r0 = xq[(size_t)e0.x * 32 + lane];
        uint2 r1 = xq[(size_t)e1.x * 32 + lane];
        float n0 = __int_as_float(e0.y), n1 = __int_as_float(e1.y);
        a0 = fmaf(blo(r0.x), n0, a0); a1 = fmaf(bhi(r0.x), n0, a1);
        a2 = fmaf(blo(r0.y), n0, a2); a3 = fmaf(bhi(r0.y), n0, a3);
        b0 = fmaf(blo(r1.x), n1, b0); b1 = fmaf(bhi(r1.x), n1, b1);
        b2 = fmaf(blo(r1.y), n1, b2); b3 = fmaf(bhi(r1.y), n1, b3);
    }
    if (j < j1) {
        int2 e0 = epack[j];
        uint2 r0 = xq[(size_t)e0.x * 32 + lane];
        float n0 = __int_as_float(e0.y);
        a0 = fmaf(blo(r0.x), n0, a0); a1 = fmaf(bhi(r0.x), n0, a1);
        a2 = fmaf(blo(r0.y), n0, a2); a3 = fmaf(bhi(r0.y), n0, a3);
    }
    float4 res = {a0 + b0, a1 + b1, a2 + b2, a3 + b3};
    reinterpret_cast<float4*>(outf)[(size_t)c * 32 + lane] = res;
}

// ---------------------------------------------------------------- BatchNorm stats
__global__ void k_bnstats(const float* __restrict__ x, float* __restrict__ stat) {
    int d = threadIdx.x & 127;
    int sub = threadIdx.x >> 7;
    float s = 0.f, s2 = 0.f;
    for (int n = blockIdx.x * 2 + sub; n < NN; n += gridDim.x * 2) {
        float v = x[(size_t)n * NDIM + d];
        s += v;
        s2 = fmaf(v, v, s2);
    }
    __shared__ float red[256];
    red[threadIdx.x] = s;
    __syncthreads();
    if (threadIdx.x < 128) atomicAdd(&stat[threadIdx.x], red[threadIdx.x] + red[threadIdx.x + 128]);
    __syncthreads();
    red[threadIdx.x] = s2;
    __syncthreads();
    if (threadIdx.x < 128) atomicAdd(&stat[128 + threadIdx.x], red[threadIdx.x] + red[threadIdx.x + 128]);
}

__global__ void k_bnfinal(const float* __restrict__ stat, float* __restrict__ mi) {
    int d = threadIdx.x;   // 128 threads
    float m = stat[d] * (1.f / (float)NN);
    float v = stat[128 + d] * (1.f / (float)NN) - m * m;  // biased var (torch BN)
    mi[d] = m;
    mi[128 + d] = rsqrtf(v + 1e-5f);
}

// sum of relu((x-mu)*inv), read-only (x stays raw)
__global__ void k_bnsum(const float* __restrict__ x, const float* __restrict__ mi,
                        float* __restrict__ ssum) {
    __shared__ float red[256];
    float local = 0.f;
    for (int i = blockIdx.x * blockDim.x + threadIdx.x; i < NTOT;
         i += gridDim.x * blockDim.x) {
        int d = i & 127;
        local += fmaxf((x[i] - mi[d]) * mi[128 + d], 0.f);
    }
    red[threadIdx.x] = local;
    __syncthreads();
    for (int s = 128; s > 0; s >>= 1) {
        if (threadIdx.x < s) red[threadIdx.x] += red[threadIdx.x + s];
        __syncthreads();
    }
    if (threadIdx.x == 0) atomicAdd(ssum, red[0]);
}

// ---------------------------------------------------------------- SE attention -> folded bf16 WcT
// WcT[o][k] = bf16( y[m(k)] * cnnw[o*384 + k] )  (cnnw is already [o][m,d] = [o][k])
__global__ void k_attn_wc(const float* __restrict__ ssum, const float* __restrict__ fc1w,
                          const float* __restrict__ fc1b, const float* __restrict__ fc2w,
                          const float* __restrict__ fc2b, const float* __restrict__ cnnw,
                          unsigned short* __restrict__ WcT) {
    __shared__ float ysh[NM];
    if (threadIdx.x == 0) {
        float s[NM], h[6 * NM];
        for (int m = 0; m < NM; ++m) s[m] = ssum[m] * (1.f / (float)NTOT);
        for (int j = 0; j < 6 * NM; ++j) {
            float a = fc1b[j];
            for (int m = 0; m < NM; ++m) a = fmaf(s[m], fc1w[j * NM + m], a);
            h[j] = fmaxf(a, 0.f);
        }
        for (int m = 0; m < NM; ++m) {
            float a = fc2b[m];
            for (int j = 0; j < 6 * NM; ++j) a = fmaf(h[j], fc2w[m * 6 * NM + j], a);
            ysh[m] = 1.f / (1.f + expf(-a));
        }
    }
    __syncthreads();
    for (int idx = threadIdx.x; idx < NM * NDIM * NDIM; idx += blockDim.x) {
        int k = idx % (NM * NDIM);
        int m = k >> 7;
        WcT[idx] = f2bf(ysh[m] * cnnw[idx]);
    }
}

// ================================================================ launch
extern "C" void kernel_launch(void* const* d_in, const int* in_sizes, int n_in,
                              void* d_out, int out_size, void* d_ws, size_t ws_size,
                              hipStream_t stream) {
    const float* feat = (const float*)d_in[0];   // [3,50000,64]
    const int*   adj  = (const int*)d_in[1];     // [3,2,600000]
    const float* ew   = (const float*)d_in[2];   // [3,600000]
    const float* w1   = (const float*)d_in[3];   // [64,128]
    const float* w2   = (const float*)d_in[5];   // [128,128]
    const float* fc1w = (const float*)d_in[7];   // [18,3]
    const float* fc1b = (const float*)d_in[8];   // [18]
    const float* fc2w = (const float*)d_in[9];   // [3,18]
    const float* fc2b = (const float*)d_in[10];  // [3]
    const float* cnnw = (const float*)d_in[11];  // [128,3,128,1]
    const float* cnnb = (const float*)d_in[12];  // [128]
    float* out = (float*)d_out;

    float* ws = (float*)d_ws;
    size_t off = 0;
    unsigned short* xwb = (unsigned short*)(ws + off); off += NTOT / 2;  // bf16 XW
    float* bufB = ws + off; off += NTOT;   // aggregate (f32)
    float* x2b[NM];
    x2b[0] = ws + off; off += NTOT;
    x2b[1] = ws + off; off += NTOT;
    x2b[2] = out;                          // d_out doubles as branch-2 raw agg
    float* dis  = ws + off; off += NN;
    int*   cnt  = (int*)(ws + off); off += NN;
    int*   ptr  = (int*)(ws + off); off += NN + 4;
    int*   bsum = (int*)(ws + off); off += 256;
    float* stat6 = ws + off; off += 6 * 256;
    float* ssum = ws + off; off += 4;
    float* mi1  = ws + off; off += 256;
    float* mi2  = ws + off; off += NM * 256;
    unsigned short* w1t = (unsigned short*)(ws + off); off += 128 * 64 / 2;
    unsigned short* w2t = (unsigned short*)(ws + off); off += 128 * 128 / 2;
    unsigned short* WcT = (unsigned short*)(ws + off); off += NM * NDIM * NDIM / 2;
    int2*  epack = (int2*)(ws + off); off += 2 * NE;

    const int EB = (NE + 255) / 256;
    const int GB = (NN + 127) / 128;   // MFMA GEMM blocks (391)

    k_fill<<<(6 * 256 + 4 + 255) / 256, 256, 0, stream>>>(stat6, 0.f, 6 * 256 + 4);
    k_prepw<<<96, 256, 0, stream>>>(w1, w2, w1t, w2t);

    for (int m = 0; m < NM; ++m) {
        const float* fm   = feat + (size_t)m * NN * NF;
        const int*   rowp = adj + (size_t)m * 2 * NE;
        const int*   colp = rowp + NE;
        const float* ewm  = ew + (size_t)m * NE;
        float* x2 = x2b[m];
        float* st1 = stat6 + (m * 2 + 0) * 256;
        float* st2 = stat6 + (m * 2 + 1) * 256;

        k_init_dc<<<NB_SCAN, 256, 0, stream>>>(dis, cnt);
        k_deg_count<<<EB, 256, 0, stream>>>(colp, ewm, dis, cnt);
        k_scan1<<<NB_SCAN, 256, 0, stream>>>(cnt, ptr, bsum, dis);
        k_scan2<<<1, 256, 0, stream>>>(bsum);
        k_scan3<<<NB_SCAN, 256, 0, stream>>>(ptr, bsum, cnt);
        k_fill_csr<<<EB, 256, 0, stream>>>(rowp, colp, ewm, dis, ptr, cnt, epack);

        // ---- layer 1: X@W1 (MFMA, bf16 out) -> gather -> stats
        k_mgemm<NF, false><<<GB, 256, 0, stream>>>(fm, w1t, nullptr, xwb);
        k_gather<<<NN / 8, 256, 0, stream>>>(xwb, dis, ptr, epack, bufB);
        k_bnstats<<<1024, 256, 0, stream>>>(bufB, st1);
        k_bnfinal<<<1, 128, 0, stream>>>(st1, mi1);

        // ---- layer 2: BN(relu)@W2 (MFMA) -> gather -> stats; SE sum read-only
        k_mgemm<NDIM, true><<<GB, 256, 0, stream>>>(bufB, w2t, mi1, xwb);
        k_gather<<<NN / 8, 256, 0, stream>>>(xwb, dis, ptr, epack, x2);
        k_bnstats<<<1024, 256, 0, stream>>>(x2, st2);
        k_bnfinal<<<1, 128, 0, stream>>>(st2, mi2 + m * 256);
        k_bnsum<<<1024, 256, 0, stream>>>(x2, mi2 + m * 256, ssum + m);
    }

    // SE attention -> scaled bf16 WcT, then final [N,384]@[384,128] MFMA GEMM
    k_attn_wc<<<1, 256, 0, stream>>>(ssum, fc1w, fc1b, fc2w, fc2b, cnnw, WcT);
    k_mfinal<<<GB, 256, 0, stream>>>(x2b[0], x2b[1], x2b[2], mi2, WcT, cnnb, out);
}

// Round 5
// 652.775 us; speedup vs baseline: 4.4347x; 1.5261x over previous
//
#include <hip/hip_runtime.h>

#define NN   50000      // nodes
#define NF   64         // input features
#define NDIM 128        // hidden / output dim
#define NE   600000     // edges
#define NM   3          // graphs
#define NTOT (NN * NDIM)
#define NB_SCAN 196     // ceil(NN/256)
#define PTRSZ (NN + 1)

typedef __attribute__((ext_vector_type(8))) short short8;
typedef __attribute__((ext_vector_type(4))) float f32x4;

__device__ __forceinline__ unsigned short f2bf(float x) {
    unsigned int u = __float_as_uint(x);
    return (unsigned short)((u + 0x7FFFu + ((u >> 16) & 1u)) >> 16);  // RNE
}
__device__ __forceinline__ float blo(unsigned int u) { return __uint_as_float(u << 16); }
__device__ __forceinline__ float bhi(unsigned int u) { return __uint_as_float(u & 0xFFFF0000u); }

// ---------------------------------------------------------------- init: dis=1, cnt=0, stats=0
__global__ void k_init(float* __restrict__ dis, int* __restrict__ cnt,
                       float* __restrict__ stat) {
    int i = blockIdx.x * 256 + threadIdx.x;
    if (i < NM * NN) { dis[i] = 1.0f; cnt[i] = 0; }
    if (i < 6 * 256 + 8) stat[i] = 0.f;   // stat6 + ssum
}

// ---------------------------------------------------------------- weight prep (bf16, transposed)
// w1t[n][k]=bf16(w1[k][n]); w2t[n][k]=bf16(w2[k][n]); wcb[o][k]=bf16(cnnw[o][k])
__global__ void k_prepw(const float* __restrict__ w1, const float* __restrict__ w2,
                        const float* __restrict__ cnnw, unsigned short* __restrict__ w1t,
                        unsigned short* __restrict__ w2t, unsigned short* __restrict__ wcb) {
    int i = blockIdx.x * 256 + threadIdx.x;
    if (i < 8192) {
        int n = i >> 6, k = i & 63;
        w1t[i] = f2bf(w1[k * 128 + n]);
    } else if (i < 8192 + 16384) {
        int j = i - 8192;
        int n = j >> 7, k = j & 127;
        w2t[j] = f2bf(w2[k * 128 + n]);
    } else if (i < 8192 + 16384 + 49152) {
        int j = i - 24576;
        wcb[j] = f2bf(cnnw[j]);
    }
}

// ---------------------------------------------------------------- degree + count (all m)
__global__ void k_deg_count(const int* __restrict__ adj, const float* __restrict__ ew,
                            float* __restrict__ dis, int* __restrict__ cnt) {
    int e = blockIdx.x * 256 + threadIdx.x;
    if (e >= NM * NE) return;
    int m = e / NE, el = e - m * NE;
    int c = adj[m * 2 * NE + NE + el];
    atomicAdd(&dis[m * NN + c], ew[e]);
    atomicAdd(&cnt[m * NN + c], 1);
}

// ---------------------------------------------------------------- CSR build (batched, y = m)
__global__ void k_scan1(const int* __restrict__ cntB, int* __restrict__ ptrB,
                        int* __restrict__ bsumB, float* __restrict__ disB) {
    const int m = blockIdx.y;
    const int* cnt = cntB + m * NN;
    int* ptr = ptrB + m * PTRSZ;
    int* bsum = bsumB + m * 256;
    float* dis = disB + m * NN;
    __shared__ int s[256];
    int i = blockIdx.x * 256 + threadIdx.x;
    int v = (i < NN) ? cnt[i] : 0;
    if (i < NN) dis[i] = rsqrtf(dis[i]);
    s[threadIdx.x] = v;
    __syncthreads();
    for (int off = 1; off < 256; off <<= 1) {
        int x = (threadIdx.x >= off) ? s[threadIdx.x - off] : 0;
        __syncthreads();
        s[threadIdx.x] += x;
        __syncthreads();
    }
    if (i < NN) ptr[i] = s[threadIdx.x] - v;
    if (threadIdx.x == 255) bsum[blockIdx.x] = s[255];
}

__global__ void k_scan2(int* __restrict__ bsumB) {   // 3 blocks, one per m
    int* bsum = bsumB + blockIdx.x * 256;
    __shared__ int s[256];
    int t = threadIdx.x;
    int v = (t < NB_SCAN) ? bsum[t] : 0;
    s[t] = v;
    __syncthreads();
    for (int off = 1; off < 256; off <<= 1) {
        int x = (t >= off) ? s[t - off] : 0;
        __syncthreads();
        s[t] += x;
        __syncthreads();
    }
    bsum[t] = s[t] - v;
}

__global__ void k_scan3(int* __restrict__ ptrB, const int* __restrict__ bsumB,
                        int* __restrict__ cntB) {
    const int m = blockIdx.y;
    int* ptr = ptrB + m * PTRSZ;
    int i = blockIdx.x * 256 + threadIdx.x;
    if (i < NN) {
        ptr[i] += bsumB[m * 256 + (i >> 8)];
        cntB[m * NN + i] = 0;
    }
    if (i == 0) ptr[NN] = NE;
}

__global__ void k_fill_csr(const int* __restrict__ adj, const float* __restrict__ ew,
                           const float* __restrict__ disB, const int* __restrict__ ptrB,
                           int* __restrict__ fillB, int2* __restrict__ epackB) {
    int e = blockIdx.x * 256 + threadIdx.x;
    if (e >= NM * NE) return;
    int m = e / NE, el = e - m * NE;
    int r = adj[m * 2 * NE + el];
    int c = adj[m * 2 * NE + NE + el];
    int slot = atomicAdd(&fillB[m * NN + c], 1);
    float nrm = disB[m * NN + r] * ew[e] * disB[m * NN + c];
    epackB[m * NE + ptrB[m * PTRSZ + c] + slot] = make_int2(r, __float_as_int(nrm));
}

// ---------------------------------------------------------------- MFMA GEMM (batched over m)
// out_bf[n,o] = bf16( sum_k A[n,k]*W[k,o] ); A f32 or bf16 (+opt BN fold), Wt bf16 [128][K].
template<int K, bool ABF16, bool BN>
__global__ __launch_bounds__(256, 2) void k_mgemm(const void* __restrict__ Abase,
                                                  const unsigned short* __restrict__ Wt,
                                                  const float* __restrict__ miB,
                                                  unsigned short* __restrict__ outB) {
    __shared__ unsigned short sA[128 * 72];
    __shared__ unsigned short sB[128 * 72];
    const int m = blockIdx.y;
    const float* Af = (const float*)Abase + (size_t)m * NN * K;
    const unsigned int* Au = (const unsigned int*)Abase + (size_t)m * NN * (K / 2);
    const float* mi = BN ? miB + m * 256 : nullptr;
    unsigned short* outb = outB + (size_t)m * NTOT;
    const int tid = threadIdx.x;
    const int lane = tid & 63, wave = tid >> 6;
    const int llo = lane & 15, lhi = lane >> 4;
    const int row0 = blockIdx.x * 128;
    const int waveR0 = wave * 32;
    const unsigned int* Wtu = reinterpret_cast<const unsigned int*>(Wt);
    f32x4 acc[2][8];
#pragma unroll
    for (int i = 0; i < 2; ++i)
#pragma unroll
        for (int t = 0; t < 8; ++t) acc[i][t] = (f32x4){0.f, 0.f, 0.f, 0.f};

    for (int ch = 0; ch < K / 64; ++ch) {
        const int kc0 = ch * 64;
        for (int idx = tid; idx < 4096; idx += 256) {
            int r = idx >> 5, kk2 = idx & 31;
            int g = row0 + r;
            float vx = 0.f, vy = 0.f;
            if (g < NN) {
                if (ABF16) {
                    unsigned int u = Au[(size_t)g * (K / 2) + kc0 / 2 + kk2];
                    vx = blo(u); vy = bhi(u);
                } else {
                    float2 v = *reinterpret_cast<const float2*>(Af + (size_t)g * K + kc0 + kk2 * 2);
                    vx = v.x; vy = v.y;
                }
                if (BN) {
                    int d0 = kc0 + kk2 * 2;
                    vx = fmaxf((vx - mi[d0]) * mi[128 + d0], 0.f);
                    vy = fmaxf((vy - mi[d0 + 1]) * mi[128 + d0 + 1], 0.f);
                }
            }
            reinterpret_cast<unsigned int*>(sA)[r * 36 + kk2] =
                (unsigned int)f2bf(vx) | ((unsigned int)f2bf(vy) << 16);
        }
        for (int idx = tid; idx < 4096; idx += 256) {
            int n = idx >> 5, kk2 = idx & 31;
            reinterpret_cast<unsigned int*>(sB)[n * 36 + kk2] =
                Wtu[n * (K / 2) + kc0 / 2 + kk2];
        }
        __syncthreads();
#pragma unroll
        for (int ks = 0; ks < 64; ks += 32) {
            short8 a0 = *reinterpret_cast<const short8*>(sA + (waveR0 + llo) * 72 + ks + lhi * 8);
            short8 a1 = *reinterpret_cast<const short8*>(sA + (waveR0 + 16 + llo) * 72 + ks + lhi * 8);
#pragma unroll
            for (int t = 0; t < 8; ++t) {
                short8 b = *reinterpret_cast<const short8*>(sB + (t * 16 + llo) * 72 + ks + lhi * 8);
                acc[0][t] = __builtin_amdgcn_mfma_f32_16x16x32_bf16(a0, b, acc[0][t], 0, 0, 0);
                acc[1][t] = __builtin_amdgcn_mfma_f32_16x16x32_bf16(a1, b, acc[1][t], 0, 0, 0);
            }
        }
        __syncthreads();
    }
#pragma unroll
    for (int rt = 0; rt < 2; ++rt)
#pragma unroll
        for (int r = 0; r < 4; ++r) {
            int grow = row0 + waveR0 + rt * 16 + lhi * 4 + r;
            if (grow < NN) {
#pragma unroll
                for (int t = 0; t < 8; ++t)
                    outb[(size_t)grow * NDIM + t * 16 + llo] = f2bf(acc[rt][t][r]);
            }
        }
}

// ---------------------------------------------------------------- CSR gather (bf16 in/out, f32 acc, batched)
__global__ void k_gather(const unsigned short* __restrict__ xwB, const float* __restrict__ disB,
                         const int* __restrict__ ptrB, const int2* __restrict__ epackB,
                         unsigned short* __restrict__ outB) {
    const int m = blockIdx.y;
    const uint2* xq = reinterpret_cast<const uint2*>(xwB + (size_t)m * NTOT);
    const float* dis = disB + m * NN;
    const int* ptr = ptrB + m * PTRSZ;
    const int2* epack = epackB + (size_t)m * NE;
    int sub = threadIdx.x >> 5;
    int lane = threadIdx.x & 31;
    int c = blockIdx.x * 8 + sub;
    float ds = dis[c];
    float s2 = ds * ds;
    uint2 sv = xq[(size_t)c * 32 + lane];
    float a0 = blo(sv.x) * s2, a1 = bhi(sv.x) * s2;
    float a2 = blo(sv.y) * s2, a3 = bhi(sv.y) * s2;
    float b0 = 0.f, b1 = 0.f, b2 = 0.f, b3 = 0.f;
    int j = ptr[c], j1 = ptr[c + 1];
    for (; j + 1 < j1; j += 2) {
        int2 e0 = epack[j], e1 = epack[j + 1];
        uint2 r0 = xq[(size_t)e0.x * 32 + lane];
        uint2 r1 = xq[(size_t)e1.x * 32 + lane];
        float n0 = __int_as_float(e0.y), n1 = __int_as_float(e1.y);
        a0 = fmaf(blo(r0.x), n0, a0); a1 = fmaf(bhi(r0.x), n0, a1);
        a2 = fmaf(blo(r0.y), n0, a2); a3 = fmaf(bhi(r0.y), n0, a3);
        b0 = fmaf(blo(r1.x), n1, b0); b1 = fmaf(bhi(r1.x), n1, b1);
        b2 = fmaf(blo(r1.y), n1, b2); b3 = fmaf(bhi(r1.y), n1, b3);
    }
    if (j < j1) {
        int2 e0 = epack[j];
        uint2 r0 = xq[(size_t)e0.x * 32 + lane];
        float n0 = __int_as_float(e0.y);
        a0 = fmaf(blo(r0.x), n0, a0); a1 = fmaf(bhi(r0.x), n0, a1);
        a2 = fmaf(blo(r0.y), n0, a2); a3 = fmaf(bhi(r0.y), n0, a3);
    }
    uint2 res;
    res.x = (unsigned int)f2bf(a0 + b0) | ((unsigned int)f2bf(a1 + b1) << 16);
    res.y = (unsigned int)f2bf(a2 + b2) | ((unsigned int)f2bf(a3 + b3) << 16);
    reinterpret_cast<uint2*>(outB + (size_t)m * NTOT)[(size_t)c * 32 + lane] = res;
}

// ---------------------------------------------------------------- BatchNorm stats (bf16 input, batched)
__global__ void k_bnstats(const unsigned short* __restrict__ xB, float* __restrict__ statB) {
    const int m = blockIdx.y;
    const unsigned int* xu = reinterpret_cast<const unsigned int*>(xB + (size_t)m * NTOT);
    float* stat = statB + m * 256;
    int d2 = threadIdx.x & 63;
    int sub = threadIdx.x >> 6;
    float slo = 0.f, shi = 0.f, qlo = 0.f, qhi = 0.f;
    for (int n = blockIdx.x * 4 + sub; n < NN; n += gridDim.x * 4) {
        unsigned int u = xu[(size_t)n * 64 + d2];
        float a = blo(u), b = bhi(u);
        slo += a; shi += b;
        qlo = fmaf(a, a, qlo); qhi = fmaf(b, b, qhi);
    }
    __shared__ float red[256];
    red[threadIdx.x] = slo; __syncthreads();
    if (sub == 0) atomicAdd(&stat[2 * d2], red[d2] + red[d2 + 64] + red[d2 + 128] + red[d2 + 192]);
    __syncthreads();
    red[threadIdx.x] = shi; __syncthreads();
    if (sub == 0) atomicAdd(&stat[2 * d2 + 1], red[d2] + red[d2 + 64] + red[d2 + 128] + red[d2 + 192]);
    __syncthreads();
    red[threadIdx.x] = qlo; __syncthreads();
    if (sub == 0) atomicAdd(&stat[128 + 2 * d2], red[d2] + red[d2 + 64] + red[d2 + 128] + red[d2 + 192]);
    __syncthreads();
    red[threadIdx.x] = qhi; __syncthreads();
    if (sub == 0) atomicAdd(&stat[128 + 2 * d2 + 1], red[d2] + red[d2 + 64] + red[d2 + 128] + red[d2 + 192]);
}

__global__ void k_bnfinal(const float* __restrict__ statB, float* __restrict__ miB) {
    const float* stat = statB + blockIdx.x * 256;
    float* mi = miB + blockIdx.x * 256;
    int d = threadIdx.x;   // 128 threads
    float m = stat[d] * (1.f / (float)NN);
    float v = stat[128 + d] * (1.f / (float)NN) - m * m;  // biased var (torch BN)
    mi[d] = m;
    mi[128 + d] = rsqrtf(v + 1e-5f);
}

// sum of relu((x-mu)*inv) over all elements (bf16 input, batched)
__global__ void k_bnsum(const unsigned short* __restrict__ xB, const float* __restrict__ miB,
                        float* __restrict__ ssum) {
    const int m = blockIdx.y;
    const unsigned int* xu = reinterpret_cast<const unsigned int*>(xB + (size_t)m * NTOT);
    const float* mi = miB + m * 256;
    float local = 0.f;
    for (unsigned int i = blockIdx.x * 256 + threadIdx.x; i < NTOT / 2; i += gridDim.x * 256) {
        unsigned int u = xu[i];
        int c = (i & 63) * 2;
        local += fmaxf((blo(u) - mi[c]) * mi[128 + c], 0.f)
               + fmaxf((bhi(u) - mi[c + 1]) * mi[129 + c], 0.f);
    }
    __shared__ float red[256];
    red[threadIdx.x] = local;
    __syncthreads();
    for (int s = 128; s > 0; s >>= 1) {
        if (threadIdx.x < s) red[threadIdx.x] += red[threadIdx.x + s];
        __syncthreads();
    }
    if (threadIdx.x == 0) atomicAdd(&ssum[m], red[0]);
}

// ---------------------------------------------------------------- SE attention: y[3] only (wave-parallel)
__global__ void k_attn_y(const float* __restrict__ ssum, const float* __restrict__ fc1w,
                         const float* __restrict__ fc1b, const float* __restrict__ fc2w,
                         const float* __restrict__ fc2b, float* __restrict__ yv) {
    __shared__ float h[6 * NM], sv[NM];
    int t = threadIdx.x;
    if (t < NM) sv[t] = ssum[t] * (1.f / (float)NTOT);
    __syncthreads();
    if (t < 6 * NM) {
        float a = fc1b[t];
        for (int mm = 0; mm < NM; ++mm) a = fmaf(sv[mm], fc1w[t * NM + mm], a);
        h[t] = fmaxf(a, 0.f);
    }
    __syncthreads();
    if (t < NM) {
        float a = fc2b[t];
        for (int j = 0; j < 6 * NM; ++j) a = fmaf(h[j], fc2w[t * 6 * NM + j], a);
        yv[t] = 1.f / (1.f + expf(-a));
    }
}

// ---------------------------------------------------------------- final MFMA GEMM (K=384, bf16 x2, BN+y fold, +bias)
__global__ __launch_bounds__(256, 2) void k_mfinal(const unsigned short* __restrict__ xB,
                                                   const float* __restrict__ miB,
                                                   const unsigned short* __restrict__ wcb,
                                                   const float* __restrict__ yv,
                                                   const float* __restrict__ cnnb,
                                                   float* __restrict__ out) {
    __shared__ unsigned short sA[128 * 72];
    __shared__ unsigned short sB[128 * 72];
    const int tid = threadIdx.x;
    const int lane = tid & 63, wave = tid >> 6;
    const int llo = lane & 15, lhi = lane >> 4;
    const int row0 = blockIdx.x * 128;
    const int waveR0 = wave * 32;
    const unsigned int* Wtu = reinterpret_cast<const unsigned int*>(wcb);
    f32x4 acc[2][8];
#pragma unroll
    for (int i = 0; i < 2; ++i)
#pragma unroll
        for (int t = 0; t < 8; ++t) acc[i][t] = (f32x4){0.f, 0.f, 0.f, 0.f};

#pragma unroll
    for (int ch = 0; ch < 6; ++ch) {
        const int m = ch >> 1;
        const int dbase = (ch & 1) * 64;
        const unsigned int* Au = reinterpret_cast<const unsigned int*>(xB + (size_t)m * NTOT);
        const float* mi = miB + m * 256;
        const float ym = yv[m];
        for (int idx = tid; idx < 4096; idx += 256) {
            int r = idx >> 5, kk2 = idx & 31;
            int g = row0 + r;
            float vx = 0.f, vy = 0.f;
            if (g < NN) {
                unsigned int u = Au[(size_t)g * 64 + dbase / 2 + kk2];
                int c = dbase + kk2 * 2;
                vx = fmaxf((blo(u) - mi[c]) * mi[128 + c], 0.f) * ym;
                vy = fmaxf((bhi(u) - mi[c + 1]) * mi[129 + c], 0.f) * ym;
            }
            reinterpret_cast<unsigned int*>(sA)[r * 36 + kk2] =
                (unsigned int)f2bf(vx) | ((unsigned int)f2bf(vy) << 16);
        }
        for (int idx = tid; idx < 4096; idx += 256) {
            int n = idx >> 5, kk2 = idx & 31;
            reinterpret_cast<unsigned int*>(sB)[n * 36 + kk2] = Wtu[n * 192 + ch * 32 + kk2];
        }
        __syncthreads();
#pragma unroll
        for (int ks = 0; ks < 64; ks += 32) {
            short8 a0 = *reinterpret_cast<const short8*>(sA + (waveR0 + llo) * 72 + ks + lhi * 8);
            short8 a1 = *reinterpret_cast<const short8*>(sA + (waveR0 + 16 + llo) * 72 + ks + lhi * 8);
#pragma unroll
            for (int t = 0; t < 8; ++t) {
                short8 b = *reinterpret_cast<const short8*>(sB + (t * 16 + llo) * 72 + ks + lhi * 8);
                acc[0][t] = __builtin_amdgcn_mfma_f32_16x16x32_bf16(a0, b, acc[0][t], 0, 0, 0);
                acc[1][t] = __builtin_amdgcn_mfma_f32_16x16x32_bf16(a1, b, acc[1][t], 0, 0, 0);
            }
        }
        __syncthreads();
    }
#pragma unroll
    for (int rt = 0; rt < 2; ++rt)
#pragma unroll
        for (int r = 0; r < 4; ++r) {
            int grow = row0 + waveR0 + rt * 16 + lhi * 4 + r;
            if (grow < NN) {
#pragma unroll
                for (int t = 0; t < 8; ++t)
                    out[(size_t)grow * NDIM + t * 16 + llo] = acc[rt][t][r] + cnnb[t * 16 + llo];
            }
        }
}

// ================================================================ launch
extern "C" void kernel_launch(void* const* d_in, const int* in_sizes, int n_in,
                              void* d_out, int out_size, void* d_ws, size_t ws_size,
                              hipStream_t stream) {
    const float* feat = (const float*)d_in[0];   // [3,50000,64]
    const int*   adj  = (const int*)d_in[1];     // [3,2,600000]
    const float* ew   = (const float*)d_in[2];   // [3,600000]
    const float* w1   = (const float*)d_in[3];   // [64,128]
    const float* w2   = (const float*)d_in[5];   // [128,128]
    const float* fc1w = (const float*)d_in[7];   // [18,3]
    const float* fc1b = (const float*)d_in[8];   // [18]
    const float* fc2w = (const float*)d_in[9];   // [3,18]
    const float* fc2b = (const float*)d_in[10];  // [3]
    const float* cnnw = (const float*)d_in[11];  // [128,3,128,1] == [128][384]
    const float* cnnb = (const float*)d_in[12];  // [128]
    float* out = (float*)d_out;

    float* ws = (float*)d_ws;
    size_t off = 0;
    unsigned short* xwb  = (unsigned short*)(ws + off); off += NM * NTOT / 2;  // bf16 GEMM out
    unsigned short* aggX = (unsigned short*)(ws + off); off += NM * NTOT / 2;  // bf16 agg1, then x2
    int2*  epack = (int2*)(ws + off); off += NM * NE * 2;
    float* dis  = ws + off; off += NM * NN;
    int*   cnt  = (int*)(ws + off); off += NM * NN;
    int*   ptr  = (int*)(ws + off); off += NM * PTRSZ + 13;  // keep alignment
    int*   bsum = (int*)(ws + off); off += NM * 256;
    float* stat6 = ws + off; off += 6 * 256;
    float* ssum = ws + off; off += 8;                         // zeroed with stat6
    float* mi1  = ws + off; off += NM * 256;
    float* mi2  = ws + off; off += NM * 256;
    float* yv   = ws + off; off += 8;
    unsigned short* w1t = (unsigned short*)(ws + off); off += 8192 / 2;
    unsigned short* w2t = (unsigned short*)(ws + off); off += 16384 / 2;
    unsigned short* wcb = (unsigned short*)(ws + off); off += 49152 / 2;

    const int EB3 = (NM * NE + 255) / 256;       // 7032
    const int GB  = (NN + 127) / 128;            // 391
    dim3 gGemm(GB, NM), gGath(NN / 8, NM), gScan(NB_SCAN, NM);
    dim3 gStat(512, NM), gSum(512, NM);

    k_init<<<(NM * NN + 255) / 256, 256, 0, stream>>>(dis, cnt, stat6);
    k_prepw<<<288, 256, 0, stream>>>(w1, w2, cnnw, w1t, w2t, wcb);

    // CSR build, all m at once
    k_deg_count<<<EB3, 256, 0, stream>>>(adj, ew, dis, cnt);
    k_scan1<<<gScan, 256, 0, stream>>>(cnt, ptr, bsum, dis);
    k_scan2<<<NM, 256, 0, stream>>>(bsum);
    k_scan3<<<gScan, 256, 0, stream>>>(ptr, bsum, cnt);
    k_fill_csr<<<EB3, 256, 0, stream>>>(adj, ew, dis, ptr, cnt, epack);

    // layer 1: X@W1 -> gather -> stats
    k_mgemm<NF, false, false><<<gGemm, 256, 0, stream>>>(feat, w1t, nullptr, xwb);
    k_gather<<<gGath, 256, 0, stream>>>(xwb, dis, ptr, epack, aggX);
    k_bnstats<<<gStat, 256, 0, stream>>>(aggX, stat6);
    k_bnfinal<<<NM, 128, 0, stream>>>(stat6, mi1);

    // layer 2: BN(relu)@W2 -> gather -> stats -> SE sums
    k_mgemm<NDIM, true, true><<<gGemm, 256, 0, stream>>>(aggX, w2t, mi1, xwb);
    k_gather<<<gGath, 256, 0, stream>>>(xwb, dis, ptr, epack, aggX);
    k_bnstats<<<gStat, 256, 0, stream>>>(aggX, stat6 + NM * 256);
    k_bnfinal<<<NM, 128, 0, stream>>>(stat6 + NM * 256, mi2);
    k_bnsum<<<gSum, 256, 0, stream>>>(aggX, mi2, ssum);

    // SE y -> final fused GEMM
    k_attn_y<<<1, 64, 0, stream>>>(ssum, fc1w, fc1b, fc2w, fc2b, yv);
    k_mfinal<<<GB, 256, 0, stream>>>(aggX, mi2, wcb, yv, cnnb, out);
}

// Round 6
// 516.116 us; speedup vs baseline: 5.6090x; 1.2648x over previous
//
#include <hip/hip_runtime.h>

#define NN   50000      // nodes
#define NF   64         // input features
#define NDIM 128        // hidden / output dim
#define NE   600000     // edges
#define NM   3          // graphs
#define NTOT (NN * NDIM)
#define NB_SCAN 196     // ceil(NN/256)
#define PTRSZ (NN + 1)

typedef __attribute__((ext_vector_type(8))) short short8;
typedef __attribute__((ext_vector_type(4))) float f32x4;
typedef unsigned long long u64;

__device__ __forceinline__ unsigned short f2bf(float x) {
    unsigned int u = __float_as_uint(x);
    return (unsigned short)((u + 0x7FFFu + ((u >> 16) & 1u)) >> 16);  // RNE
}
__device__ __forceinline__ float blo(unsigned int u) { return __uint_as_float(u << 16); }
__device__ __forceinline__ float bhi(unsigned int u) { return __uint_as_float(u & 0xFFFF0000u); }

// ---------------------------------------------------------------- init: cnt64=0, stats=0
__global__ void k_init(u64* __restrict__ cnt64, float* __restrict__ stat) {
    int i = blockIdx.x * 256 + threadIdx.x;
    if (i < NM * NN) cnt64[i] = 0ULL;
    if (i < 6 * 256 + 8) stat[i] = 0.f;   // stat6 + ssum
}

// ---------------------------------------------------------------- weight prep (bf16, transposed)
__global__ void k_prepw(const float* __restrict__ w1, const float* __restrict__ w2,
                        const float* __restrict__ cnnw, unsigned short* __restrict__ w1t,
                        unsigned short* __restrict__ w2t, unsigned short* __restrict__ wcb) {
    int i = blockIdx.x * 256 + threadIdx.x;
    if (i < 8192) {
        int n = i >> 6, k = i & 63;
        w1t[i] = f2bf(w1[k * 128 + n]);
    } else if (i < 8192 + 16384) {
        int j = i - 8192;
        int n = j >> 7, k = j & 127;
        w2t[j] = f2bf(w2[k * 128 + n]);
    } else if (i < 8192 + 16384 + 49152) {
        int j = i - 24576;
        wcb[j] = f2bf(cnnw[j]);
    }
}

// ---------------------------------------------------------------- degree + count + slot, ONE u64 atomic/edge
// cnt64[c] accumulates ((1<<44) | ew*2^24); old>>44 is this edge's slot in its segment.
__global__ void k_deg_count(const int* __restrict__ adj, const float* __restrict__ ew,
                            u64* __restrict__ cnt64, int* __restrict__ slot) {
    int e = blockIdx.x * 256 + threadIdx.x;
    if (e >= NM * NE) return;
    int m = e / NE, el = e - m * NE;
    int c = adj[m * 2 * NE + NE + el];
    u64 enc = (1ULL << 44) | (u64)(ew[e] * 16777216.0f);
    u64 old = atomicAdd(&cnt64[m * NN + c], enc);
    slot[e] = (int)(old >> 44);
}

// ---------------------------------------------------------------- CSR build (batched, y = m)
// dis = rsqrt(1 + fixed-point degree sum); ptr = exclusive scan of counts
__global__ void k_scan1(const u64* __restrict__ cnt64B, int* __restrict__ ptrB,
                        int* __restrict__ bsumB, float* __restrict__ disB) {
    const int m = blockIdx.y;
    const u64* cnt64 = cnt64B + m * NN;
    int* ptr = ptrB + m * PTRSZ;
    int* bsum = bsumB + m * 256;
    float* dis = disB + m * NN;
    __shared__ int s[256];
    int i = blockIdx.x * 256 + threadIdx.x;
    int v = 0;
    if (i < NN) {
        u64 u = cnt64[i];
        v = (int)(u >> 44);
        dis[i] = rsqrtf(1.0f + (float)(u & 0xFFFFFFFFFFFULL) * (1.f / 16777216.f));
    }
    s[threadIdx.x] = v;
    __syncthreads();
    for (int off = 1; off < 256; off <<= 1) {
        int x = (threadIdx.x >= off) ? s[threadIdx.x - off] : 0;
        __syncthreads();
        s[threadIdx.x] += x;
        __syncthreads();
    }
    if (i < NN) ptr[i] = s[threadIdx.x] - v;
    if (threadIdx.x == 255) bsum[blockIdx.x] = s[255];
}

__global__ void k_scan2(int* __restrict__ bsumB) {   // 3 blocks, one per m
    int* bsum = bsumB + blockIdx.x * 256;
    __shared__ int s[256];
    int t = threadIdx.x;
    int v = (t < NB_SCAN) ? bsum[t] : 0;
    s[t] = v;
    __syncthreads();
    for (int off = 1; off < 256; off <<= 1) {
        int x = (t >= off) ? s[t - off] : 0;
        __syncthreads();
        s[t] += x;
        __syncthreads();
    }
    bsum[t] = s[t] - v;
}

__global__ void k_scan3(int* __restrict__ ptrB, const int* __restrict__ bsumB) {
    const int m = blockIdx.y;
    int* ptr = ptrB + m * PTRSZ;
    int i = blockIdx.x * 256 + threadIdx.x;
    if (i < NN) ptr[i] += bsumB[m * 256 + (i >> 8)];
    if (i == 0) ptr[NN] = NE;
}

// atomic-free: slot gives the position inside each column segment
__global__ void k_fill_csr(const int* __restrict__ adj, const float* __restrict__ ew,
                           const float* __restrict__ disB, const int* __restrict__ ptrB,
                           const int* __restrict__ slot, int2* __restrict__ epackB) {
    int e = blockIdx.x * 256 + threadIdx.x;
    if (e >= NM * NE) return;
    int m = e / NE, el = e - m * NE;
    int r = adj[m * 2 * NE + el];
    int c = adj[m * 2 * NE + NE + el];
    float nrm = disB[m * NN + r] * ew[e] * disB[m * NN + c];
    epackB[(size_t)m * NE + ptrB[m * PTRSZ + c] + slot[e]] = make_int2(r, __float_as_int(nrm));
}

// ---------------------------------------------------------------- MFMA GEMM (batched over m)
// out_bf[n,o] = bf16( sum_k A[n,k]*W[k,o] ); BN: relu((a-mean)*invstd) folded on A-load,
// (mean,invstd) computed in-block from raw stats.
template<int K, bool ABF16, bool BN>
__global__ __launch_bounds__(256, 2) void k_mgemm(const void* __restrict__ Abase,
                                                  const unsigned short* __restrict__ Wt,
                                                  const float* __restrict__ statB,
                                                  unsigned short* __restrict__ outB) {
    __shared__ unsigned short sA[128 * 72];
    __shared__ unsigned short sB[128 * 72];
    __shared__ float smi[256];
    const int m = blockIdx.y;
    const float* Af = (const float*)Abase + (size_t)m * NN * K;
    const unsigned int* Au = (const unsigned int*)Abase + (size_t)m * NN * (K / 2);
    unsigned short* outb = outB + (size_t)m * NTOT;
    const int tid = threadIdx.x;
    const int lane = tid & 63, wave = tid >> 6;
    const int llo = lane & 15, lhi = lane >> 4;
    const int row0 = blockIdx.x * 128;
    const int waveR0 = wave * 32;
    const unsigned int* Wtu = reinterpret_cast<const unsigned int*>(Wt);
    if (BN) {
        const float* stat = statB + m * 256;
        if (tid < 128) {
            float mean = stat[tid] * (1.f / (float)NN);
            float var = stat[128 + tid] * (1.f / (float)NN) - mean * mean;
            smi[tid] = mean;
            smi[128 + tid] = rsqrtf(var + 1e-5f);
        }
        __syncthreads();
    }
    f32x4 acc[2][8];
#pragma unroll
    for (int i = 0; i < 2; ++i)
#pragma unroll
        for (int t = 0; t < 8; ++t) acc[i][t] = (f32x4){0.f, 0.f, 0.f, 0.f};

    for (int ch = 0; ch < K / 64; ++ch) {
        const int kc0 = ch * 64;
        for (int idx = tid; idx < 4096; idx += 256) {
            int r = idx >> 5, kk2 = idx & 31;
            int g = row0 + r;
            float vx = 0.f, vy = 0.f;
            if (g < NN) {
                if (ABF16) {
                    unsigned int u = Au[(size_t)g * (K / 2) + kc0 / 2 + kk2];
                    vx = blo(u); vy = bhi(u);
                } else {
                    float2 v = *reinterpret_cast<const float2*>(Af + (size_t)g * K + kc0 + kk2 * 2);
                    vx = v.x; vy = v.y;
                }
                if (BN) {
                    int d0 = kc0 + kk2 * 2;
                    vx = fmaxf((vx - smi[d0]) * smi[128 + d0], 0.f);
                    vy = fmaxf((vy - smi[d0 + 1]) * smi[128 + d0 + 1], 0.f);
                }
            }
            reinterpret_cast<unsigned int*>(sA)[r * 36 + kk2] =
                (unsigned int)f2bf(vx) | ((unsigned int)f2bf(vy) << 16);
        }
        for (int idx = tid; idx < 4096; idx += 256) {
            int n = idx >> 5, kk2 = idx & 31;
            reinterpret_cast<unsigned int*>(sB)[n * 36 + kk2] =
                Wtu[n * (K / 2) + kc0 / 2 + kk2];
        }
        __syncthreads();
#pragma unroll
        for (int ks = 0; ks < 64; ks += 32) {
            short8 a0 = *reinterpret_cast<const short8*>(sA + (waveR0 + llo) * 72 + ks + lhi * 8);
            short8 a1 = *reinterpret_cast<const short8*>(sA + (waveR0 + 16 + llo) * 72 + ks + lhi * 8);
#pragma unroll
            for (int t = 0; t < 8; ++t) {
                short8 b = *reinterpret_cast<const short8*>(sB + (t * 16 + llo) * 72 + ks + lhi * 8);
                acc[0][t] = __builtin_amdgcn_mfma_f32_16x16x32_bf16(a0, b, acc[0][t], 0, 0, 0);
                acc[1][t] = __builtin_amdgcn_mfma_f32_16x16x32_bf16(a1, b, acc[1][t], 0, 0, 0);
            }
        }
        __syncthreads();
    }
#pragma unroll
    for (int rt = 0; rt < 2; ++rt)
#pragma unroll
        for (int r = 0; r < 4; ++r) {
            int grow = row0 + waveR0 + rt * 16 + lhi * 4 + r;
            if (grow < NN) {
#pragma unroll
                for (int t = 0; t < 8; ++t)
                    outb[(size_t)grow * NDIM + t * 16 + llo] = f2bf(acc[rt][t][r]);
            }
        }
}

// ---------------------------------------------------------------- CSR gather (bf16 in/out, f32 acc, batched)
__global__ void k_gather(const unsigned short* __restrict__ xwB, const float* __restrict__ disB,
                         const int* __restrict__ ptrB, const int2* __restrict__ epackB,
                         unsigned short* __restrict__ outB) {
    const int m = blockIdx.y;
    const uint2* xq = reinterpret_cast<const uint2*>(xwB + (size_t)m * NTOT);
    const float* dis = disB + m * NN;
    const int* ptr = ptrB + m * PTRSZ;
    const int2* epack = epackB + (size_t)m * NE;
    int sub = threadIdx.x >> 5;
    int lane = threadIdx.x & 31;
    int c = blockIdx.x * 8 + sub;
    float ds = dis[c];
    float s2 = ds * ds;
    uint2 sv = xq[(size_t)c * 32 + lane];
    float a0 = blo(sv.x) * s2, a1 = bhi(sv.x) * s2;
    float a2 = blo(sv.y) * s2, a3 = bhi(sv.y) * s2;
    float b0 = 0.f, b1 = 0.f, b2 = 0.f, b3 = 0.f;
    int j = ptr[c], j1 = ptr[c + 1];
    for (; j + 1 < j1; j += 2) {
        int2 e0 = epack[j], e1 = epack[j + 1];
        uint2 r0 = xq[(size_t)e0.x * 32 + lane];
        uint2 r1 = xq[(size_t)e1.x * 32 + lane];
        float n0 = __int_as_float(e0.y), n1 = __int_as_float(e1.y);
        a0 = fmaf(blo(r0.x), n0, a0); a1 = fmaf(bhi(r0.x), n0, a1);
        a2 = fmaf(blo(r0.y), n0, a2); a3 = fmaf(bhi(r0.y), n0, a3);
        b0 = fmaf(blo(r1.x), n1, b0); b1 = fmaf(bhi(r1.x), n1, b1);
        b2 = fmaf(blo(r1.y), n1, b2); b3 = fmaf(bhi(r1.y), n1, b3);
    }
    if (j < j1) {
        int2 e0 = epack[j];
        uint2 r0 = xq[(size_t)e0.x * 32 + lane];
        float n0 = __int_as_float(e0.y);
        a0 = fmaf(blo(r0.x), n0, a0); a1 = fmaf(bhi(r0.x), n0, a1);
        a2 = fmaf(blo(r0.y), n0, a2); a3 = fmaf(bhi(r0.y), n0, a3);
    }
    uint2 res;
    res.x = (unsigned int)f2bf(a0 + b0) | ((unsigned int)f2bf(a1 + b1) << 16);
    res.y = (unsigned int)f2bf(a2 + b2) | ((unsigned int)f2bf(a3 + b3) << 16);
    reinterpret_cast<uint2*>(outB + (size_t)m * NTOT)[(size_t)c * 32 + lane] = res;
}

// ---------------------------------------------------------------- BatchNorm stats (bf16 input, batched)
__global__ void k_bnstats(const unsigned short* __restrict__ xB, float* __restrict__ statB) {
    const int m = blockIdx.y;
    const unsigned int* xu = reinterpret_cast<const unsigned int*>(xB + (size_t)m * NTOT);
    float* stat = statB + m * 256;
    int d2 = threadIdx.x & 63;
    int sub = threadIdx.x >> 6;
    float slo = 0.f, shi = 0.f, qlo = 0.f, qhi = 0.f;
    for (int n = blockIdx.x * 4 + sub; n < NN; n += gridDim.x * 4) {
        unsigned int u = xu[(size_t)n * 64 + d2];
        float a = blo(u), b = bhi(u);
        slo += a; shi += b;
        qlo = fmaf(a, a, qlo); qhi = fmaf(b, b, qhi);
    }
    __shared__ float red[256];
    red[threadIdx.x] = slo; __syncthreads();
    if (sub == 0) atomicAdd(&stat[2 * d2], red[d2] + red[d2 + 64] + red[d2 + 128] + red[d2 + 192]);
    __syncthreads();
    red[threadIdx.x] = shi; __syncthreads();
    if (sub == 0) atomicAdd(&stat[2 * d2 + 1], red[d2] + red[d2 + 64] + red[d2 + 128] + red[d2 + 192]);
    __syncthreads();
    red[threadIdx.x] = qlo; __syncthreads();
    if (sub == 0) atomicAdd(&stat[128 + 2 * d2], red[d2] + red[d2 + 64] + red[d2 + 128] + red[d2 + 192]);
    __syncthreads();
    red[threadIdx.x] = qhi; __syncthreads();
    if (sub == 0) atomicAdd(&stat[128 + 2 * d2 + 1], red[d2] + red[d2 + 64] + red[d2 + 128] + red[d2 + 192]);
}

// sum of relu((x-mean)*invstd); (mean,invstd) computed in-block from stats
__global__ void k_bnsum(const unsigned short* __restrict__ xB, const float* __restrict__ statB,
                        float* __restrict__ ssum) {
    const int m = blockIdx.y;
    const unsigned int* xu = reinterpret_cast<const unsigned int*>(xB + (size_t)m * NTOT);
    __shared__ float smi[256];
    {
        const float* stat = statB + m * 256;
        if (threadIdx.x < 128) {
            float mean = stat[threadIdx.x] * (1.f / (float)NN);
            float var = stat[128 + threadIdx.x] * (1.f / (float)NN) - mean * mean;
            smi[threadIdx.x] = mean;
            smi[128 + threadIdx.x] = rsqrtf(var + 1e-5f);
        }
        __syncthreads();
    }
    float local = 0.f;
    for (unsigned int i = blockIdx.x * 256 + threadIdx.x; i < NTOT / 2; i += gridDim.x * 256) {
        unsigned int u = xu[i];
        int c = (i & 63) * 2;
        local += fmaxf((blo(u) - smi[c]) * smi[128 + c], 0.f)
               + fmaxf((bhi(u) - smi[c + 1]) * smi[129 + c], 0.f);
    }
    __shared__ float red[256];
    red[threadIdx.x] = local;
    __syncthreads();
    for (int s = 128; s > 0; s >>= 1) {
        if (threadIdx.x < s) red[threadIdx.x] += red[threadIdx.x + s];
        __syncthreads();
    }
    if (threadIdx.x == 0) atomicAdd(&ssum[m], red[0]);
}

// ---------------------------------------------------------------- SE attention: y[3] (wave-parallel)
__global__ void k_attn_y(const float* __restrict__ ssum, const float* __restrict__ fc1w,
                         const float* __restrict__ fc1b, const float* __restrict__ fc2w,
                         const float* __restrict__ fc2b, float* __restrict__ yv) {
    __shared__ float h[6 * NM], sv[NM];
    int t = threadIdx.x;
    if (t < NM) sv[t] = ssum[t] * (1.f / (float)NTOT);
    __syncthreads();
    if (t < 6 * NM) {
        float a = fc1b[t];
        for (int mm = 0; mm < NM; ++mm) a = fmaf(sv[mm], fc1w[t * NM + mm], a);
        h[t] = fmaxf(a, 0.f);
    }
    __syncthreads();
    if (t < NM) {
        float a = fc2b[t];
        for (int j = 0; j < 6 * NM; ++j) a = fmaf(h[j], fc2w[t * 6 * NM + j], a);
        yv[t] = 1.f / (1.f + expf(-a));
    }
}

// ---------------------------------------------------------------- final MFMA GEMM (K=384, BN+y fold, +bias)
__global__ __launch_bounds__(256, 2) void k_mfinal(const unsigned short* __restrict__ xB,
                                                   const float* __restrict__ statB,
                                                   const unsigned short* __restrict__ wcb,
                                                   const float* __restrict__ yv,
                                                   const float* __restrict__ cnnb,
                                                   float* __restrict__ out) {
    __shared__ unsigned short sA[128 * 72];
    __shared__ unsigned short sB[128 * 72];
    __shared__ float smi[768];
    const int tid = threadIdx.x;
    const int lane = tid & 63, wave = tid >> 6;
    const int llo = lane & 15, lhi = lane >> 4;
    const int row0 = blockIdx.x * 128;
    const int waveR0 = wave * 32;
    const unsigned int* Wtu = reinterpret_cast<const unsigned int*>(wcb);
    for (int t = tid; t < 384; t += 256) {
        int mm = t >> 7, d = t & 127;
        const float* stat = statB + mm * 256;
        float mean = stat[d] * (1.f / (float)NN);
        float var = stat[128 + d] * (1.f / (float)NN) - mean * mean;
        smi[mm * 256 + d] = mean;
        smi[mm * 256 + 128 + d] = rsqrtf(var + 1e-5f);
    }
    __syncthreads();
    f32x4 acc[2][8];
#pragma unroll
    for (int i = 0; i < 2; ++i)
#pragma unroll
        for (int t = 0; t < 8; ++t) acc[i][t] = (f32x4){0.f, 0.f, 0.f, 0.f};

#pragma unroll
    for (int ch = 0; ch < 6; ++ch) {
        const int m = ch >> 1;
        const int dbase = (ch & 1) * 64;
        const unsigned int* Au = reinterpret_cast<const unsigned int*>(xB + (size_t)m * NTOT);
        const float* mi = smi + m * 256;
        const float ym = yv[m];
        for (int idx = tid; idx < 4096; idx += 256) {
            int r = idx >> 5, kk2 = idx & 31;
            int g = row0 + r;
            float vx = 0.f, vy = 0.f;
            if (g < NN) {
                unsigned int u = Au[(size_t)g * 64 + dbase / 2 + kk2];
                int c = dbase + kk2 * 2;
                vx = fmaxf((blo(u) - mi[c]) * mi[128 + c], 0.f) * ym;
                vy = fmaxf((bhi(u) - mi[c + 1]) * mi[129 + c], 0.f) * ym;
            }
            reinterpret_cast<unsigned int*>(sA)[r * 36 + kk2] =
                (unsigned int)f2bf(vx) | ((unsigned int)f2bf(vy) << 16);
        }
        for (int idx = tid; idx < 4096; idx += 256) {
            int n = idx >> 5, kk2 = idx & 31;
            reinterpret_cast<unsigned int*>(sB)[n * 36 + kk2] = Wtu[n * 192 + ch * 32 + kk2];
        }
        __syncthreads();
#pragma unroll
        for (int ks = 0; ks < 64; ks += 32) {
            short8 a0 = *reinterpret_cast<const short8*>(sA + (waveR0 + llo) * 72 + ks + lhi * 8);
            short8 a1 = *reinterpret_cast<const short8*>(sA + (waveR0 + 16 + llo) * 72 + ks + lhi * 8);
#pragma unroll
            for (int t = 0; t < 8; ++t) {
                short8 b = *reinterpret_cast<const short8*>(sB + (t * 16 + llo) * 72 + ks + lhi * 8);
                acc[0][t] = __builtin_amdgcn_mfma_f32_16x16x32_bf16(a0, b, acc[0][t], 0, 0, 0);
                acc[1][t] = __builtin_amdgcn_mfma_f32_16x16x32_bf16(a1, b, acc[1][t], 0, 0, 0);
            }
        }
        __syncthreads();
    }
#pragma unroll
    for (int rt = 0; rt < 2; ++rt)
#pragma unroll
        for (int r = 0; r < 4; ++r) {
            int grow = row0 + waveR0 + rt * 16 + lhi * 4 + r;
            if (grow < NN) {
#pragma unroll
                for (int t = 0; t < 8; ++t)
                    out[(size_t)grow * NDIM + t * 16 + llo] = acc[rt][t][r] + cnnb[t * 16 + llo];
            }
        }
}

// ================================================================ launch
extern "C" void kernel_launch(void* const* d_in, const int* in_sizes, int n_in,
                              void* d_out, int out_size, void* d_ws, size_t ws_size,
                              hipStream_t stream) {
    const float* feat = (const float*)d_in[0];   // [3,50000,64]
    const int*   adj  = (const int*)d_in[1];     // [3,2,600000]
    const float* ew   = (const float*)d_in[2];   // [3,600000]
    const float* w1   = (const float*)d_in[3];   // [64,128]
    const float* w2   = (const float*)d_in[5];   // [128,128]
    const float* fc1w = (const float*)d_in[7];   // [18,3]
    const float* fc1b = (const float*)d_in[8];   // [18]
    const float* fc2w = (const float*)d_in[9];   // [3,18]
    const float* fc2b = (const float*)d_in[10];  // [3]
    const float* cnnw = (const float*)d_in[11];  // [128,3,128,1] == [128][384]
    const float* cnnb = (const float*)d_in[12];  // [128]
    float* out = (float*)d_out;

    float* ws = (float*)d_ws;
    size_t off = 0;
    unsigned short* xwb  = (unsigned short*)(ws + off); off += NM * NTOT / 2;  // bf16 GEMM out
    unsigned short* aggX = (unsigned short*)(ws + off); off += NM * NTOT / 2;  // bf16 agg1, then x2
    int2*  epack = (int2*)(ws + off); off += NM * NE * 2;
    u64*   cnt64 = (u64*)(ws + off); off += NM * NN * 2;
    int*   slot  = (int*)(ws + off); off += NM * NE;
    float* dis  = ws + off; off += NM * NN;
    int*   ptr  = (int*)(ws + off); off += NM * PTRSZ + 13;  // keep alignment
    int*   bsum = (int*)(ws + off); off += NM * 256;
    float* stat6 = ws + off; off += 6 * 256;
    float* ssum = ws + off; off += 8;                         // zeroed with stat6
    float* yv   = ws + off; off += 8;
    unsigned short* w1t = (unsigned short*)(ws + off); off += 8192 / 2;
    unsigned short* w2t = (unsigned short*)(ws + off); off += 16384 / 2;
    unsigned short* wcb = (unsigned short*)(ws + off); off += 49152 / 2;

    const int EB3 = (NM * NE + 255) / 256;       // 7032
    const int GB  = (NN + 127) / 128;            // 391
    dim3 gGemm(GB, NM), gGath(NN / 8, NM), gScan(NB_SCAN, NM);
    dim3 gStat(512, NM), gSum(512, NM);

    k_init<<<(NM * NN + 255) / 256, 256, 0, stream>>>(cnt64, stat6);
    k_prepw<<<288, 256, 0, stream>>>(w1, w2, cnnw, w1t, w2t, wcb);

    // CSR build, all m at once; single u64 atomic/edge yields deg, cnt AND slot
    k_deg_count<<<EB3, 256, 0, stream>>>(adj, ew, cnt64, slot);
    k_scan1<<<gScan, 256, 0, stream>>>(cnt64, ptr, bsum, dis);
    k_scan2<<<NM, 256, 0, stream>>>(bsum);
    k_scan3<<<gScan, 256, 0, stream>>>(ptr, bsum);
    k_fill_csr<<<EB3, 256, 0, stream>>>(adj, ew, dis, ptr, slot, epack);

    // layer 1: X@W1 -> gather -> stats
    k_mgemm<NF, false, false><<<gGemm, 256, 0, stream>>>(feat, w1t, nullptr, xwb);
    k_gather<<<gGath, 256, 0, stream>>>(xwb, dis, ptr, epack, aggX);
    k_bnstats<<<gStat, 256, 0, stream>>>(aggX, stat6);

    // layer 2: BN(relu)@W2 -> gather -> stats -> SE sums
    k_mgemm<NDIM, true, true><<<gGemm, 256, 0, stream>>>(aggX, w2t, stat6, xwb);
    k_gather<<<gGath, 256, 0, stream>>>(xwb, dis, ptr, epack, aggX);
    k_bnstats<<<gStat, 256, 0, stream>>>(aggX, stat6 + NM * 256);
    k_bnsum<<<gSum, 256, 0, stream>>>(aggX, stat6 + NM * 256, ssum);

    // SE y -> final fused GEMM
    k_attn_y<<<1, 64, 0, stream>>>(ssum, fc1w, fc1b, fc2w, fc2b, yv);
    k_mfinal<<<GB, 256, 0, stream>>>(aggX, stat6 + NM * 256, wcb, yv, cnnb, out);
}